// Round 9
// baseline (526.615 us; speedup 1.0000x reference)
//
#include <hip/hip_runtime.h>
#include <hip/hip_bf16.h>

#define N_NODES 20000
#define E_EDGES 320000
#define FEAT 128
#define CDIM 256
#define NHEAD 8
#define HDIM 32
#define NLAYER 5
#define TDIM 64
#define MSLOT 10
#define MDIM 128
#define NCLS 2

typedef unsigned short ushort_t;
typedef unsigned char uchar_t;
typedef short short8 __attribute__((ext_vector_type(8)));
typedef float floatx4 __attribute__((ext_vector_type(4)));
typedef float floatx2 __attribute__((ext_vector_type(2)));

__device__ __forceinline__ ushort_t f2bf(float f) {
    union { float f; unsigned int u; } t; t.f = f;
    unsigned int r = (t.u + 0x7FFF + ((t.u >> 16) & 1)) >> 16;
    return (ushort_t)r;
}
__device__ __forceinline__ float bf2f(ushort_t u) {
    union { float f; unsigned int u; } t; t.u = ((unsigned int)u) << 16;
    return t.f;
}

// ---------------------------------------------------------------------------
// bf16 MFMA GEMM, BM=32, BN=128, BK=64. grid (2, M/32) = 1250 blocks.
// LDS: A 4 KB + B 16 KB = 20 KB. K-loop has half the barriers of BK=32.
// Swizzle: chunk (8 elems) at LDS col c holds global chunk gc=(c-(row>>1))&7;
// read side sw = ((kstep*4+lq) + (row>>1)) & 7 -> 2-way bank alias (free).
// ---------------------------------------------------------------------------
__global__ __launch_bounds__(256) void gemm_mfma(
    const ushort_t* __restrict__ A1, int lda1, int K1,
    const ushort_t* __restrict__ A2, int lda2, int Ktot,
    const ushort_t* __restrict__ Bt,
    const float* __restrict__ bias,
    ushort_t* Cbf, int doRelu)
{
    __shared__ __align__(16) ushort_t smemA[32 * 64];
    __shared__ __align__(16) ushort_t smemB[128 * 64];
    int tid = threadIdx.x;
    int lane = tid & 63, wid = tid >> 6;
    int li = lane & 15, lq = lane >> 4;
    int row0 = blockIdx.y * 32;
    int col0 = blockIdx.x * 128;

    floatx4 acc[2][2];
#pragma unroll
    for (int a = 0; a < 2; a++)
#pragma unroll
        for (int b = 0; b < 2; b++) acc[a][b] = {0.f, 0.f, 0.f, 0.f};

    int ar = tid >> 3, ac = tid & 7;
    int agc = (ac - (ar >> 1)) & 7;

    for (int k0 = 0; k0 < Ktot; k0 += 64) {
        __syncthreads();
        const ushort_t* Ab; int lda;
        if (k0 < K1) { Ab = A1 + k0; lda = lda1; }
        else         { Ab = A2 + (k0 - K1); lda = lda2; }
        {
            const void* g = (const void*)(Ab + (size_t)(row0 + ar) * lda + agc * 8);
            __builtin_amdgcn_global_load_lds(
                (const __attribute__((address_space(1))) void*)g,
                (__attribute__((address_space(3))) void*)&smemA[wid * 512], 16, 0, 0);
        }
#pragma unroll
        for (int j = 0; j < 4; j++) {
            int slot = j * 256 + tid;
            int n = slot >> 3, c = slot & 7;
            int gc = (c - (n >> 1)) & 7;
            const void* g = (const void*)(Bt + (size_t)(col0 + n) * Ktot + k0 + gc * 8);
            __builtin_amdgcn_global_load_lds(
                (const __attribute__((address_space(1))) void*)g,
                (__attribute__((address_space(3))) void*)&smemB[(j * 256 + wid * 64) * 8], 16, 0, 0);
        }
        __syncthreads();

#pragma unroll
        for (int ks = 0; ks < 2; ks++) {
            short8 af[2], bfr[2];
#pragma unroll
            for (int mt = 0; mt < 2; mt++) {
                int m = mt * 16 + li;
                int sw = ((ks * 4 + lq) + (m >> 1)) & 7;
                af[mt] = *(const short8*)&smemA[m * 64 + sw * 8];
            }
#pragma unroll
            for (int nt = 0; nt < 2; nt++) {
                int nl = wid * 32 + nt * 16 + li;
                int sw = ((ks * 4 + lq) + (nl >> 1)) & 7;
                bfr[nt] = *(const short8*)&smemB[nl * 64 + sw * 8];
            }
#pragma unroll
            for (int mt = 0; mt < 2; mt++)
#pragma unroll
                for (int nt = 0; nt < 2; nt++)
                    acc[mt][nt] = __builtin_amdgcn_mfma_f32_16x16x32_bf16(af[mt], bfr[nt], acc[mt][nt], 0, 0, 0);
        }
    }

#pragma unroll
    for (int mt = 0; mt < 2; mt++) {
        int row = row0 + mt * 16 + lq * 4;
#pragma unroll
        for (int nt = 0; nt < 2; nt++) {
            int col = col0 + wid * 32 + nt * 16 + li;
            float bv = bias ? bias[col] : 0.f;
#pragma unroll
            for (int r = 0; r < 4; r++) {
                float v = acc[mt][nt][r] + bv;
                if (doRelu) v = fmaxf(v, 0.f);
                Cbf[(size_t)(row + r) * CDIM + col] = f2bf(v);
            }
        }
    }
}

// h-GEMM (BM=32,BN=128,BK=64): writes h in fp8 e4m3 + fused head logits.
// Wave wid's 32 cols = exactly head hd = blockIdx.x*4+wid.
__global__ __launch_bounds__(256) void gemm_h(
    const ushort_t* __restrict__ A1, int lda1, int K1,
    const ushort_t* __restrict__ A2, int lda2, int Ktot,
    const ushort_t* __restrict__ Bt,
    const float* __restrict__ a_s, const float* __restrict__ a_d,
    uchar_t* __restrict__ Cf8,
    float* __restrict__ esrc, float* __restrict__ edst)
{
    __shared__ __align__(16) ushort_t smemA[32 * 64];
    __shared__ __align__(16) ushort_t smemB[128 * 64];
    int tid = threadIdx.x;
    int lane = tid & 63, wid = tid >> 6;
    int li = lane & 15, lq = lane >> 4;
    int row0 = blockIdx.y * 32;
    int col0 = blockIdx.x * 128;

    floatx4 acc[2][2];
#pragma unroll
    for (int a = 0; a < 2; a++)
#pragma unroll
        for (int b = 0; b < 2; b++) acc[a][b] = {0.f, 0.f, 0.f, 0.f};

    int ar = tid >> 3, ac = tid & 7;
    int agc = (ac - (ar >> 1)) & 7;

    for (int k0 = 0; k0 < Ktot; k0 += 64) {
        __syncthreads();
        const ushort_t* Ab; int lda;
        if (k0 < K1) { Ab = A1 + k0; lda = lda1; }
        else         { Ab = A2 + (k0 - K1); lda = lda2; }
        {
            const void* g = (const void*)(Ab + (size_t)(row0 + ar) * lda + agc * 8);
            __builtin_amdgcn_global_load_lds(
                (const __attribute__((address_space(1))) void*)g,
                (__attribute__((address_space(3))) void*)&smemA[wid * 512], 16, 0, 0);
        }
#pragma unroll
        for (int j = 0; j < 4; j++) {
            int slot = j * 256 + tid;
            int n = slot >> 3, c = slot & 7;
            int gc = (c - (n >> 1)) & 7;
            const void* g = (const void*)(Bt + (size_t)(col0 + n) * Ktot + k0 + gc * 8);
            __builtin_amdgcn_global_load_lds(
                (const __attribute__((address_space(1))) void*)g,
                (__attribute__((address_space(3))) void*)&smemB[(j * 256 + wid * 64) * 8], 16, 0, 0);
        }
        __syncthreads();

#pragma unroll
        for (int ks = 0; ks < 2; ks++) {
            short8 af[2], bfr[2];
#pragma unroll
            for (int mt = 0; mt < 2; mt++) {
                int m = mt * 16 + li;
                int sw = ((ks * 4 + lq) + (m >> 1)) & 7;
                af[mt] = *(const short8*)&smemA[m * 64 + sw * 8];
            }
#pragma unroll
            for (int nt = 0; nt < 2; nt++) {
                int nl = wid * 32 + nt * 16 + li;
                int sw = ((ks * 4 + lq) + (nl >> 1)) & 7;
                bfr[nt] = *(const short8*)&smemB[nl * 64 + sw * 8];
            }
#pragma unroll
            for (int mt = 0; mt < 2; mt++)
#pragma unroll
                for (int nt = 0; nt < 2; nt++)
                    acc[mt][nt] = __builtin_amdgcn_mfma_f32_16x16x32_bf16(af[mt], bfr[nt], acc[mt][nt], 0, 0, 0);
        }
    }

    int hd = blockIdx.x * 4 + wid;
    int cbase = col0 + wid * 32 + li;
    float as0 = a_s[cbase];
    float as1 = a_s[cbase + 16];
    float ad0 = a_d[cbase];
    float ad1 = a_d[cbase + 16];

#pragma unroll
    for (int mt = 0; mt < 2; mt++) {
        int row = row0 + mt * 16 + lq * 4;
#pragma unroll
        for (int r = 0; r < 4; r++) {
            float v0 = acc[mt][0][r];
            float v1 = acc[mt][1][r];
            unsigned int pk = __builtin_amdgcn_cvt_pk_fp8_f32(v0, v1, 0, false);
            Cf8[(size_t)(row + r) * CDIM + cbase]      = (uchar_t)(pk & 0xff);
            Cf8[(size_t)(row + r) * CDIM + cbase + 16] = (uchar_t)((pk >> 8) & 0xff);
            float ps = v0 * as0 + v1 * as1;
            float pd = v0 * ad0 + v1 * ad1;
#pragma unroll
            for (int d = 1; d < 16; d <<= 1) {
                ps += __shfl_xor(ps, d);
                pd += __shfl_xor(pd, d);
            }
            if (li == 0) {
                esrc[(size_t)(row + r) * NHEAD + hd] = ps;
                edst[(size_t)(row + r) * NHEAD + hd] = pd;
            }
        }
    }
}

// ---------------------------------------------------------------------------
// fp32 tiled GEMM (tiny matmuls), batched.
// ---------------------------------------------------------------------------
__global__ __launch_bounds__(256) void gemm64(
    const float* __restrict__ A, const float* __restrict__ A2,
    const float* __restrict__ B, const float* __restrict__ bias,
    float* __restrict__ C, int M, int K, int Nf, int doRelu,
    int sA, int sB, int sC)
{
    __shared__ float As[16][64];
    __shared__ float Bs[16][64];
    A += (size_t)blockIdx.z * sA;
    B += (size_t)blockIdx.z * sB;
    C += (size_t)blockIdx.z * sC;
    int tid = threadIdx.x;
    int tx = tid & 15, ty = tid >> 4;
    int row0 = blockIdx.y * 64, col0 = blockIdx.x * 64;
    int ar = tid >> 2;
    int ac = (tid & 3) * 4;

    float acc[4][4] = {};

    for (int k0 = 0; k0 < K; k0 += 16) {
        int arow = row0 + ar;
        float4 av = make_float4(0.f, 0.f, 0.f, 0.f);
        if (arow < M) {
            av = *(const float4*)(A + (size_t)arow * K + k0 + ac);
            if (A2) {
                float4 a2 = *(const float4*)(A2 + (size_t)arow * K + k0 + ac);
                av.x += a2.x; av.y += a2.y; av.z += a2.z; av.w += a2.w;
            }
        }
        As[ac + 0][ar] = av.x;
        As[ac + 1][ar] = av.y;
        As[ac + 2][ar] = av.z;
        As[ac + 3][ar] = av.w;
        float4 bv = *(const float4*)(B + (size_t)(k0 + (tid >> 4)) * Nf + col0 + (tid & 15) * 4);
        *(float4*)&Bs[tid >> 4][(tid & 15) * 4] = bv;
        __syncthreads();
#pragma unroll
        for (int kk = 0; kk < 16; kk++) {
            float4 a = *(const float4*)&As[kk][ty * 4];
            float4 b = *(const float4*)&Bs[kk][tx * 4];
            acc[0][0] += a.x * b.x; acc[0][1] += a.x * b.y; acc[0][2] += a.x * b.z; acc[0][3] += a.x * b.w;
            acc[1][0] += a.y * b.x; acc[1][1] += a.y * b.y; acc[1][2] += a.y * b.z; acc[1][3] += a.y * b.w;
            acc[2][0] += a.z * b.x; acc[2][1] += a.z * b.y; acc[2][2] += a.z * b.z; acc[2][3] += a.z * b.w;
            acc[3][0] += a.w * b.x; acc[3][1] += a.w * b.y; acc[3][2] += a.w * b.z; acc[3][3] += a.w * b.w;
        }
        __syncthreads();
    }

    float4 bv = make_float4(0.f, 0.f, 0.f, 0.f);
    if (bias) bv = *(const float4*)(bias + col0 + tx * 4);
#pragma unroll
    for (int i = 0; i < 4; i++) {
        int r = row0 + ty * 4 + i;
        if (r < M) {
            float4 o;
            o.x = acc[i][0] + bv.x;
            o.y = acc[i][1] + bv.y;
            o.z = acc[i][2] + bv.z;
            o.w = acc[i][3] + bv.w;
            if (doRelu) {
                o.x = fmaxf(o.x, 0.f); o.y = fmaxf(o.y, 0.f);
                o.z = fmaxf(o.z, 0.f); o.w = fmaxf(o.w, 0.f);
            }
            *(float4*)(C + (size_t)r * Nf + col0 + tx * 4) = o;
        }
    }
}

// ---------------------------------------------------------------------------
// Prep kernels
// ---------------------------------------------------------------------------
__global__ void cvt_bf16(const float* __restrict__ in, ushort_t* __restrict__ out, int n)
{
    int i = blockIdx.x * blockDim.x + threadIdx.x;
    if (i < n) out[i] = f2bf(in[i]);
}

__global__ __launch_bounds__(256) void transpose_cast(
    const float* __restrict__ in, int K, int Nn,
    ushort_t* __restrict__ out, int ostride, int koff,
    int inBatchStride, int outBatchStride)
{
    __shared__ float tile[32][33];
    in  += (size_t)blockIdx.z * inBatchStride;
    out += (size_t)blockIdx.z * outBatchStride;
    int k0 = blockIdx.y * 32, n0 = blockIdx.x * 32;
    int tx = threadIdx.x & 31, ty = threadIdx.x >> 5;
#pragma unroll
    for (int j = 0; j < 4; j++)
        tile[ty + j * 8][tx] = in[(size_t)(k0 + ty + j * 8) * Nn + n0 + tx];
    __syncthreads();
#pragma unroll
    for (int j = 0; j < 4; j++) {
        int n = n0 + ty + j * 8;
        out[(size_t)n * ostride + koff + k0 + tx] = f2bf(tile[tx][ty + j * 8]);
    }
}

// Wqk[l][j][d] = (1/16) * sum_c Wq[l][d][c] * kbuf[l][j][c]
__global__ __launch_bounds__(256) void wqk_build(
    const float* __restrict__ Wq, const float* __restrict__ kbufs,
    float* __restrict__ wqk)
{
    int j = blockIdx.x, l = blockIdx.y;
    int d = threadIdx.x;
    __shared__ float kk[CDIM];
    kk[d] = kbufs[((size_t)l * MSLOT + j) * CDIM + d];
    __syncthreads();
    const float* wrow = Wq + ((size_t)l * CDIM + d) * CDIM;
    float acc = 0.f;
#pragma unroll 4
    for (int c = 0; c < CDIM; c++) acc += wrow[c] * kk[c];
    wqk[((size_t)l * MSLOT + j) * CDIM + d] = acc * 0.0625f;
}

// ---------------------------------------------------------------------------
// CSR construction
// ---------------------------------------------------------------------------
__global__ void count_deg(const int* __restrict__ dst, int* __restrict__ deg, int ne)
{
    int e = blockIdx.x * blockDim.x + threadIdx.x;
    if (e < ne) atomicAdd(&deg[dst[e]], 1);
}

// single-pass exclusive scan: thread t owns 20 contiguous elements
__global__ __launch_bounds__(1024) void scan_kernel(const int* __restrict__ deg,
                                                    int* __restrict__ offs, int n)
{
    __shared__ int swt[16];
    int tid = threadIdx.x, lane = tid & 63, wid = tid >> 6;
    int base = tid * 20;
    int v[20];
    int s = 0;
#pragma unroll
    for (int i = 0; i < 20; i++) {
        int d = (base + i < n) ? deg[base + i] : 0;
        v[i] = d; s += d;
    }
    int x = s;
#pragma unroll
    for (int d = 1; d < 64; d <<= 1) {
        int t = __shfl_up(x, d);
        if (lane >= d) x += t;
    }
    if (lane == 63) swt[wid] = x;
    __syncthreads();
    if (wid == 0) {
        int w = (lane < 16) ? swt[lane] : 0;
#pragma unroll
        for (int d = 1; d < 16; d <<= 1) {
            int t = __shfl_up(w, d);
            if (lane >= d) w += t;
        }
        if (lane < 16) swt[lane] = w;
    }
    __syncthreads();
    int wbase = (wid == 0) ? 0 : swt[wid - 1];
    int run = wbase + x - s;
#pragma unroll
    for (int i = 0; i < 20; i++) {
        if (base + i < n) offs[base + i] = run;
        run += v[i];
    }
}

__global__ void fill_csr(const int* __restrict__ src, const int* __restrict__ dst,
                         const int* __restrict__ offs, int* __restrict__ cursor,
                         int* __restrict__ csr_src, int ne)
{
    int e = blockIdx.x * blockDim.x + threadIdx.x;
    if (e < ne) {
        int d = dst[e];
        int p = atomicAdd(&cursor[d], 1);
        csr_src[offs[d] + p] = src[e];
    }
}

// ---------------------------------------------------------------------------
// Fully fused GAT + cross-attn. h in fp8 e4m3. h-row gathers for the first
// 4 rounds are PREFETCHED before the softmax phase (addresses depend only on
// csr_src) so their latency overlaps the esrc gather + reductions.
// out = relu(gat + softmax(gat.Wqk).v + node_in)
// ---------------------------------------------------------------------------
__global__ __launch_bounds__(256) void gat_agg_fused(
    const uchar_t* __restrict__ h, const float* __restrict__ esrc, const float* __restrict__ edst,
    const int* __restrict__ offs, const int* __restrict__ deg, const int* __restrict__ csr_src,
    const float* __restrict__ wqk, const float* __restrict__ vbuf,
    const ushort_t* __restrict__ node_in,
    ushort_t* __restrict__ node_out, int n)
{
    int tid = threadIdx.x;
    int lane = tid & 63;
    int wslot = tid >> 6;
    int node = blockIdx.x * 4 + wslot;
    int start = offs[node], cnt = deg[node];
    int chead = lane >> 3;

    // hoisted independent loads
    ushort4 c4 = *(const ushort4*)(node_in + (size_t)node * CDIM + lane * 4);

    float4 gat4;
    if (cnt <= 64) {
        int eh = lane >> 3, hh = lane & 7;
        float edl = edst[(size_t)node * NHEAD + hh];
        int sl = (lane < cnt) ? csr_src[start + lane] : 0;
        int nit = (cnt + 7) >> 3;
        int npf = nit < 4 ? nit : 4;

        // ---- prefetch h rows (up to 32) before softmax ----
        unsigned int hw[4][8];
#pragma unroll
        for (int rr = 0; rr < 4; rr++) {
            if (rr < npf) {
#pragma unroll
                for (int k = 0; k < 8; k++) {
                    int sv = __shfl(sl, rr * 8 + k);
                    hw[rr][k] = *(const unsigned int*)(h + (size_t)sv * CDIM + lane * 4);
                }
            }
        }

        // ---- softmax over edges, (edge,head) per lane ----
        float lg[8], w8[8];
        float m = -3.0e38f;
#pragma unroll
        for (int it = 0; it < 8; it++) {
            float v = -3.0e38f;
            if (it < nit) {
                int e = it * 8 + eh;
                int se = __shfl(sl, e);
                if (e < cnt) {
                    float t = esrc[(size_t)se * NHEAD + hh] + edl;
                    v = t > 0.f ? t : 0.2f * t;
                }
            }
            lg[it] = v;
            m = fmaxf(m, v);
        }
        m = fmaxf(m, __shfl_xor(m, 8));
        m = fmaxf(m, __shfl_xor(m, 16));
        m = fmaxf(m, __shfl_xor(m, 32));
        float den = 0.f;
#pragma unroll
        for (int it = 0; it < 8; it++) {
            float w = 0.f;
            if (it < nit) {
                int e = it * 8 + eh;
                if (e < cnt) w = __expf(lg[it] - m);
            }
            w8[it] = w;
            den += w;
        }
        den += __shfl_xor(den, 8);
        den += __shfl_xor(den, 16);
        den += __shfl_xor(den, 32);
        float inv = 1.f / (den + 1e-16f);
        float invc = __shfl(inv, chead);

        // ---- consume prefetched rows ----
        float4 acc = make_float4(0.f, 0.f, 0.f, 0.f);
#pragma unroll
        for (int rr = 0; rr < 4; rr++) {
            if (rr < npf) {
                float av[8];
#pragma unroll
                for (int k = 0; k < 8; k++)
                    av[k] = __shfl(w8[rr], (k << 3) | chead);
#pragma unroll
                for (int k = 0; k < 8; k++) {
                    floatx2 lo = __builtin_amdgcn_cvt_pk_f32_fp8((int)hw[rr][k], false);
                    floatx2 hi = __builtin_amdgcn_cvt_pk_f32_fp8((int)hw[rr][k], true);
                    acc.x += av[k] * lo.x;
                    acc.y += av[k] * lo.y;
                    acc.z += av[k] * hi.x;
                    acc.w += av[k] * hi.y;
                }
            }
        }
        // ---- tail rounds (deg > 32, rare) ----
        for (int rr = 4; rr < nit; rr++) {
            int sv[8]; float av[8];
#pragma unroll
            for (int k = 0; k < 8; k++) {
                sv[k] = __shfl(sl, rr * 8 + k);
                av[k] = __shfl(w8[rr], (k << 3) | chead);
            }
#pragma unroll
            for (int k = 0; k < 8; k++) {
                unsigned int hwv = *(const unsigned int*)(h + (size_t)sv[k] * CDIM + lane * 4);
                floatx2 lo = __builtin_amdgcn_cvt_pk_f32_fp8((int)hwv, false);
                floatx2 hi = __builtin_amdgcn_cvt_pk_f32_fp8((int)hwv, true);
                acc.x += av[k] * lo.x;
                acc.y += av[k] * lo.y;
                acc.z += av[k] * hi.x;
                acc.w += av[k] * hi.y;
            }
        }
        gat4.x = fmaxf(acc.x * invc, 0.f);
        gat4.y = fmaxf(acc.y * invc, 0.f);
        gat4.z = fmaxf(acc.z * invc, 0.f);
        gat4.w = fmaxf(acc.w * invc, 0.f);
    } else {
        // slow path (deg > 64): two-pass serial (rare)
        int hh = lane & 7;
        float edl = edst[(size_t)node * NHEAD + hh];
        float m = -3.0e38f;
        int i8 = lane >> 3;
        for (int i = 0; i < cnt; i += 8) {
            int ii = i + i8;
            if (ii < cnt) {
                int s = csr_src[start + ii];
                float lgv = esrc[(size_t)s * NHEAD + hh] + edl;
                lgv = lgv > 0.f ? lgv : 0.2f * lgv;
                m = fmaxf(m, lgv);
            }
        }
        m = fmaxf(m, __shfl_xor(m, 8));
        m = fmaxf(m, __shfl_xor(m, 16));
        m = fmaxf(m, __shfl_xor(m, 32));
        float4 acc = make_float4(0.f, 0.f, 0.f, 0.f);
        float den = 0.f;
        for (int i = 0; i < cnt; i++) {
            int s = csr_src[start + i];
            float lgv = esrc[(size_t)s * NHEAD + hh] + edl;
            lgv = lgv > 0.f ? lgv : 0.2f * lgv;
            float w = __expf(lgv - m);
            den += w;
            float wc = __shfl(w, chead);
            unsigned int hwv = *(const unsigned int*)(h + (size_t)s * CDIM + lane * 4);
            floatx2 lo = __builtin_amdgcn_cvt_pk_f32_fp8((int)hwv, false);
            floatx2 hi = __builtin_amdgcn_cvt_pk_f32_fp8((int)hwv, true);
            acc.x += wc * lo.x; acc.y += wc * lo.y;
            acc.z += wc * hi.x; acc.w += wc * hi.y;
        }
        float dc = __shfl(den, chead) + 1e-16f;
        float inv = 1.f / dc;
        gat4.x = fmaxf(acc.x * inv, 0.f);
        gat4.y = fmaxf(acc.y * inv, 0.f);
        gat4.z = fmaxf(acc.z * inv, 0.f);
        gat4.w = fmaxf(acc.w * inv, 0.f);
    }

    // --- cross-attention epilogue: wqk/v direct from global (L2) ---
    float s[MSLOT];
#pragma unroll
    for (int j = 0; j < MSLOT; j++) {
        float4 w4 = *(const float4*)(wqk + j * CDIM + lane * 4);
        s[j] = gat4.x * w4.x + gat4.y * w4.y + gat4.z * w4.z + gat4.w * w4.w;
    }
#pragma unroll
    for (int d = 1; d < 64; d <<= 1) {
#pragma unroll
        for (int j = 0; j < MSLOT; j++) s[j] += __shfl_xor(s[j], d);
    }
    float m = s[0];
#pragma unroll
    for (int j = 1; j < MSLOT; j++) m = fmaxf(m, s[j]);
    float sum = 0.f;
#pragma unroll
    for (int j = 0; j < MSLOT; j++) { s[j] = __expf(s[j] - m); sum += s[j]; }
    float inv = 1.f / sum;

    float4 o;
    o.x = gat4.x + bf2f(c4.x); o.y = gat4.y + bf2f(c4.y);
    o.z = gat4.z + bf2f(c4.z); o.w = gat4.w + bf2f(c4.w);
#pragma unroll
    for (int j = 0; j < MSLOT; j++) {
        float p = s[j] * inv;
        float4 v4 = *(const float4*)(vbuf + j * CDIM + lane * 4);
        o.x += p * v4.x; o.y += p * v4.y; o.z += p * v4.z; o.w += p * v4.w;
    }
    o.x = fmaxf(o.x, 0.f); o.y = fmaxf(o.y, 0.f); o.z = fmaxf(o.z, 0.f); o.w = fmaxf(o.w, 0.f);
    ushort4 ob;
    ob.x = f2bf(o.x); ob.y = f2bf(o.y); ob.z = f2bf(o.z); ob.w = f2bf(o.w);
    *(ushort4*)(node_out + (size_t)node * CDIM + lane * 4) = ob;
}

// ---------------------------------------------------------------------------
// col_sum: vectorized bf16 reads; thread owns 4 channels, 4 rows/block/iter.
__global__ __launch_bounds__(256) void col_sum(const ushort_t* __restrict__ node,
                                               float* __restrict__ pooled, int n)
{
    int cg = (threadIdx.x & 63) * 4;
    int rofs = threadIdx.x >> 6;
    float4 acc = make_float4(0.f, 0.f, 0.f, 0.f);
    for (int r = blockIdx.x * 4 + rofs; r < n; r += gridDim.x * 4) {
        ushort4 v = *(const ushort4*)(node + (size_t)r * CDIM + cg);
        acc.x += bf2f(v.x); acc.y += bf2f(v.y); acc.z += bf2f(v.z); acc.w += bf2f(v.w);
    }
    atomicAdd(&pooled[cg + 0], acc.x);
    atomicAdd(&pooled[cg + 1], acc.y);
    atomicAdd(&pooled[cg + 2], acc.z);
    atomicAdd(&pooled[cg + 3], acc.w);
}

__global__ void finalize(const float* __restrict__ pooled, const float* __restrict__ mem,
                         const float* __restrict__ Wc, const float* __restrict__ bc,
                         float* __restrict__ out)
{
    int lane = threadIdx.x;
    float a0 = 0.f, a1 = 0.f;
    for (int i = lane; i < CDIM + MDIM; i += 64) {
        float f;
        if (i < CDIM) {
            f = pooled[i] * (1.0f / (float)N_NODES);
        } else {
            float s = 0.f;
            for (int r = 0; r < MSLOT; r++) s += mem[r * MDIM + (i - CDIM)];
            f = s * (1.0f / (float)MSLOT);
        }
        a0 += f * Wc[i * NCLS + 0];
        a1 += f * Wc[i * NCLS + 1];
    }
#pragma unroll
    for (int d = 1; d < 64; d <<= 1) { a0 += __shfl_xor(a0, d); a1 += __shfl_xor(a1, d); }
    if (lane == 0) { out[0] = a0 + bc[0]; out[1] = a1 + bc[1]; }
}

// ---------------------------------------------------------------------------
extern "C" void kernel_launch(void* const* d_in, const int* in_sizes, int n_in,
                              void* d_out, int out_size, void* d_ws, size_t ws_size,
                              hipStream_t stream)
{
    const float* x    = (const float*)d_in[0];
    const int*   ei   = (const int*)d_in[1];
    const float* temb = (const float*)d_in[2];
    const float* Wi   = (const float*)d_in[3];
    const float* bi   = (const float*)d_in[4];
    const float* Wg   = (const float*)d_in[5];
    const float* a_s  = (const float*)d_in[6];
    const float* a_d  = (const float*)d_in[7];
    const float* Wt   = (const float*)d_in[8];
    const float* Wq   = (const float*)d_in[9];
    const float* Wk   = (const float*)d_in[10];
    const float* Wv   = (const float*)d_in[11];
    const float* mem  = (const float*)d_in[12];
    const float* Wc   = (const float*)d_in[13];
    const float* bc   = (const float*)d_in[14];
    float* out = (float*)d_out;
    char* ws = (char*)d_ws;

    const size_t NCB_BYTES = (size_t)N_NODES * CDIM * 2;
    size_t off = 0;
    ushort_t* nodeA  = (ushort_t*)(ws + off); off += NCB_BYTES;
    ushort_t* nodeB  = (ushort_t*)(ws + off); off += NCB_BYTES;
    uchar_t*  hf8    = (uchar_t*)(ws + off);  off += (size_t)N_NODES * CDIM;   // 5.12 MB
    ushort_t* xbf    = (ushort_t*)(ws + off); off += (size_t)N_NODES * FEAT * 2;
    ushort_t* tembbf = (ushort_t*)(ws + off); off += (size_t)N_NODES * TDIM * 2;
    float* esrc   = (float*)(ws + off); off += (size_t)N_NODES * NHEAD * 4;
    float* edst   = (float*)(ws + off); off += (size_t)N_NODES * NHEAD * 4;
    float* kbufs  = (float*)(ws + off); off += (size_t)NLAYER * MSLOT * CDIM * 4;
    float* vbufs  = (float*)(ws + off); off += (size_t)NLAYER * MSLOT * CDIM * 4;
    float* wqkL   = (float*)(ws + off); off += (size_t)NLAYER * MSLOT * CDIM * 4;
    float* Wtp    = (float*)(ws + off); off += (size_t)NLAYER * TDIM * CDIM * 4;
    ushort_t* Bt_i = (ushort_t*)(ws + off); off += (size_t)CDIM * FEAT * 2;
    ushort_t* Bt_h = (ushort_t*)(ws + off); off += (size_t)NLAYER * CDIM * (CDIM + TDIM) * 2;
    size_t zero_base = off;
    float* pooled = (float*)(ws + off); off += CDIM * 4;
    int* deg      = (int*)(ws + off);   off += N_NODES * 4;
    int* cursor   = (int*)(ws + off);   off += N_NODES * 4;
    size_t zero_len = off - zero_base;
    int* offs     = (int*)(ws + off);   off += (N_NODES + 4) * 4;
    int* csr_src  = (int*)(ws + off);   off += (size_t)E_EDGES * 4;

    const int* srcIdx = ei;
    const int* dstIdx = ei + E_EDGES;

    hipMemsetAsync(ws + zero_base, 0, zero_len, stream);

    // ---- prep ----
    cvt_bf16<<<(N_NODES * FEAT + 255) / 256, 256, 0, stream>>>(x, xbf, N_NODES * FEAT);
    cvt_bf16<<<(N_NODES * TDIM + 255) / 256, 256, 0, stream>>>(temb, tembbf, N_NODES * TDIM);
    gemm64<<<dim3(4, 1, NLAYER), 256, 0, stream>>>(Wt, nullptr, Wg, nullptr, Wtp,
        TDIM, CDIM, CDIM, 0, TDIM * CDIM, CDIM * CDIM, TDIM * CDIM);
    transpose_cast<<<dim3(CDIM / 32, FEAT / 32, 1), 256, 0, stream>>>(
        Wi, FEAT, CDIM, Bt_i, FEAT, 0, 0, 0);
    transpose_cast<<<dim3(CDIM / 32, CDIM / 32, NLAYER), 256, 0, stream>>>(
        Wg, CDIM, CDIM, Bt_h, CDIM + TDIM, 0, CDIM * CDIM, CDIM * (CDIM + TDIM));
    transpose_cast<<<dim3(CDIM / 32, TDIM / 32, NLAYER), 256, 0, stream>>>(
        Wtp, TDIM, CDIM, Bt_h, CDIM + TDIM, CDIM, TDIM * CDIM, CDIM * (CDIM + TDIM));
    gemm64<<<dim3(4, 1, NLAYER), 256, 0, stream>>>(mem, nullptr, Wk, nullptr, kbufs,
        MSLOT, MDIM, CDIM, 0, 0, MDIM * CDIM, MSLOT * CDIM);
    gemm64<<<dim3(4, 1, NLAYER), 256, 0, stream>>>(mem, nullptr, Wv, nullptr, vbufs,
        MSLOT, MDIM, CDIM, 0, 0, MDIM * CDIM, MSLOT * CDIM);
    wqk_build<<<dim3(MSLOT, NLAYER), 256, 0, stream>>>(Wq, kbufs, wqkL);

    // ---- CSR ----
    count_deg<<<(E_EDGES + 255) / 256, 256, 0, stream>>>(dstIdx, deg, E_EDGES);
    scan_kernel<<<1, 1024, 0, stream>>>(deg, offs, N_NODES);
    fill_csr<<<(E_EDGES + 255) / 256, 256, 0, stream>>>(srcIdx, dstIdx, offs, cursor, csr_src, E_EDGES);

    dim3 mfmaGrid(2, N_NODES / 32);   // 2 x 625 = 1250 blocks
    int nodeBlocks = N_NODES / 4;

    // node = relu(x @ Wi + bi) -> nodeA (bf16)
    gemm_mfma<<<mfmaGrid, 256, 0, stream>>>(xbf, FEAT, FEAT, nullptr, 0, FEAT,
                                            Bt_i, bi, nodeA, 1);

    ushort_t* cur = nodeA;
    ushort_t* alt = nodeB;
    for (int l = 0; l < NLAYER; l++) {
        gemm_h<<<mfmaGrid, 256, 0, stream>>>(cur, CDIM, CDIM, tembbf, TDIM, CDIM + TDIM,
                                             Bt_h + (size_t)l * CDIM * (CDIM + TDIM),
                                             a_s + (size_t)l * CDIM, a_d + (size_t)l * CDIM,
                                             hf8, esrc, edst);
        gat_agg_fused<<<nodeBlocks, 256, 0, stream>>>(hf8, esrc, edst, offs, deg, csr_src,
                                                      wqkL + (size_t)l * MSLOT * CDIM,
                                                      vbufs + (size_t)l * MSLOT * CDIM,
                                                      cur, alt, N_NODES);
        ushort_t* t = cur; cur = alt; alt = t;
    }

    col_sum<<<128, 256, 0, stream>>>(cur, pooled, N_NODES);
    finalize<<<1, 64, 0, stream>>>(pooled, mem, Wc, bc, out);
}

// Round 10
// 478.405 us; speedup vs baseline: 1.1008x; 1.1008x over previous
//
#include <hip/hip_runtime.h>
#include <hip/hip_bf16.h>

#define N_NODES 20000
#define E_EDGES 320000
#define FEAT 128
#define CDIM 256
#define NHEAD 8
#define HDIM 32
#define NLAYER 5
#define TDIM 64
#define MSLOT 10
#define MDIM 128
#define NCLS 2
#define NBPOOL 200

typedef unsigned short ushort_t;
typedef unsigned char uchar_t;
typedef short short8 __attribute__((ext_vector_type(8)));
typedef float floatx4 __attribute__((ext_vector_type(4)));
typedef float floatx2 __attribute__((ext_vector_type(2)));

__device__ __forceinline__ ushort_t f2bf(float f) {
    union { float f; unsigned int u; } t; t.f = f;
    unsigned int r = (t.u + 0x7FFF + ((t.u >> 16) & 1)) >> 16;
    return (ushort_t)r;
}
__device__ __forceinline__ float bf2f(ushort_t u) {
    union { float f; unsigned int u; } t; t.u = ((unsigned int)u) << 16;
    return t.f;
}

// ---------------------------------------------------------------------------
// bf16 MFMA GEMM, BM=32, BN=128, BK=64. grid (2, M/32) = 1250 blocks.
// ---------------------------------------------------------------------------
__global__ __launch_bounds__(256) void gemm_mfma(
    const ushort_t* __restrict__ A1, int lda1, int K1,
    const ushort_t* __restrict__ A2, int lda2, int Ktot,
    const ushort_t* __restrict__ Bt,
    const float* __restrict__ bias,
    ushort_t* Cbf, int doRelu)
{
    __shared__ __align__(16) ushort_t smemA[32 * 64];
    __shared__ __align__(16) ushort_t smemB[128 * 64];
    int tid = threadIdx.x;
    int lane = tid & 63, wid = tid >> 6;
    int li = lane & 15, lq = lane >> 4;
    int row0 = blockIdx.y * 32;
    int col0 = blockIdx.x * 128;

    floatx4 acc[2][2];
#pragma unroll
    for (int a = 0; a < 2; a++)
#pragma unroll
        for (int b = 0; b < 2; b++) acc[a][b] = {0.f, 0.f, 0.f, 0.f};

    int ar = tid >> 3, ac = tid & 7;
    int agc = (ac - (ar >> 1)) & 7;

    for (int k0 = 0; k0 < Ktot; k0 += 64) {
        __syncthreads();
        const ushort_t* Ab; int lda;
        if (k0 < K1) { Ab = A1 + k0; lda = lda1; }
        else         { Ab = A2 + (k0 - K1); lda = lda2; }
        {
            const void* g = (const void*)(Ab + (size_t)(row0 + ar) * lda + agc * 8);
            __builtin_amdgcn_global_load_lds(
                (const __attribute__((address_space(1))) void*)g,
                (__attribute__((address_space(3))) void*)&smemA[wid * 512], 16, 0, 0);
        }
#pragma unroll
        for (int j = 0; j < 4; j++) {
            int slot = j * 256 + tid;
            int n = slot >> 3, c = slot & 7;
            int gc = (c - (n >> 1)) & 7;
            const void* g = (const void*)(Bt + (size_t)(col0 + n) * Ktot + k0 + gc * 8);
            __builtin_amdgcn_global_load_lds(
                (const __attribute__((address_space(1))) void*)g,
                (__attribute__((address_space(3))) void*)&smemB[(j * 256 + wid * 64) * 8], 16, 0, 0);
        }
        __syncthreads();

#pragma unroll
        for (int ks = 0; ks < 2; ks++) {
            short8 af[2], bfr[2];
#pragma unroll
            for (int mt = 0; mt < 2; mt++) {
                int m = mt * 16 + li;
                int sw = ((ks * 4 + lq) + (m >> 1)) & 7;
                af[mt] = *(const short8*)&smemA[m * 64 + sw * 8];
            }
#pragma unroll
            for (int nt = 0; nt < 2; nt++) {
                int nl = wid * 32 + nt * 16 + li;
                int sw = ((ks * 4 + lq) + (nl >> 1)) & 7;
                bfr[nt] = *(const short8*)&smemB[nl * 64 + sw * 8];
            }
#pragma unroll
            for (int mt = 0; mt < 2; mt++)
#pragma unroll
                for (int nt = 0; nt < 2; nt++)
                    acc[mt][nt] = __builtin_amdgcn_mfma_f32_16x16x32_bf16(af[mt], bfr[nt], acc[mt][nt], 0, 0, 0);
        }
    }

#pragma unroll
    for (int mt = 0; mt < 2; mt++) {
        int row = row0 + mt * 16 + lq * 4;
#pragma unroll
        for (int nt = 0; nt < 2; nt++) {
            int col = col0 + wid * 32 + nt * 16 + li;
            float bv = bias ? bias[col] : 0.f;
#pragma unroll
            for (int r = 0; r < 4; r++) {
                float v = acc[mt][nt][r] + bv;
                if (doRelu) v = fmaxf(v, 0.f);
                Cbf[(size_t)(row + r) * CDIM + col] = f2bf(v);
            }
        }
    }
}

// h-GEMM (BM=32,BN=128,BK=64): writes h in fp8 e4m3 + fused head logits.
__global__ __launch_bounds__(256) void gemm_h(
    const ushort_t* __restrict__ A1, int lda1, int K1,
    const ushort_t* __restrict__ A2, int lda2, int Ktot,
    const ushort_t* __restrict__ Bt,
    const float* __restrict__ a_s, const float* __restrict__ a_d,
    uchar_t* __restrict__ Cf8,
    float* __restrict__ esrc, float* __restrict__ edst)
{
    __shared__ __align__(16) ushort_t smemA[32 * 64];
    __shared__ __align__(16) ushort_t smemB[128 * 64];
    int tid = threadIdx.x;
    int lane = tid & 63, wid = tid >> 6;
    int li = lane & 15, lq = lane >> 4;
    int row0 = blockIdx.y * 32;
    int col0 = blockIdx.x * 128;

    floatx4 acc[2][2];
#pragma unroll
    for (int a = 0; a < 2; a++)
#pragma unroll
        for (int b = 0; b < 2; b++) acc[a][b] = {0.f, 0.f, 0.f, 0.f};

    int ar = tid >> 3, ac = tid & 7;
    int agc = (ac - (ar >> 1)) & 7;

    for (int k0 = 0; k0 < Ktot; k0 += 64) {
        __syncthreads();
        const ushort_t* Ab; int lda;
        if (k0 < K1) { Ab = A1 + k0; lda = lda1; }
        else         { Ab = A2 + (k0 - K1); lda = lda2; }
        {
            const void* g = (const void*)(Ab + (size_t)(row0 + ar) * lda + agc * 8);
            __builtin_amdgcn_global_load_lds(
                (const __attribute__((address_space(1))) void*)g,
                (__attribute__((address_space(3))) void*)&smemA[wid * 512], 16, 0, 0);
        }
#pragma unroll
        for (int j = 0; j < 4; j++) {
            int slot = j * 256 + tid;
            int n = slot >> 3, c = slot & 7;
            int gc = (c - (n >> 1)) & 7;
            const void* g = (const void*)(Bt + (size_t)(col0 + n) * Ktot + k0 + gc * 8);
            __builtin_amdgcn_global_load_lds(
                (const __attribute__((address_space(1))) void*)g,
                (__attribute__((address_space(3))) void*)&smemB[(j * 256 + wid * 64) * 8], 16, 0, 0);
        }
        __syncthreads();

#pragma unroll
        for (int ks = 0; ks < 2; ks++) {
            short8 af[2], bfr[2];
#pragma unroll
            for (int mt = 0; mt < 2; mt++) {
                int m = mt * 16 + li;
                int sw = ((ks * 4 + lq) + (m >> 1)) & 7;
                af[mt] = *(const short8*)&smemA[m * 64 + sw * 8];
            }
#pragma unroll
            for (int nt = 0; nt < 2; nt++) {
                int nl = wid * 32 + nt * 16 + li;
                int sw = ((ks * 4 + lq) + (nl >> 1)) & 7;
                bfr[nt] = *(const short8*)&smemB[nl * 64 + sw * 8];
            }
#pragma unroll
            for (int mt = 0; mt < 2; mt++)
#pragma unroll
                for (int nt = 0; nt < 2; nt++)
                    acc[mt][nt] = __builtin_amdgcn_mfma_f32_16x16x32_bf16(af[mt], bfr[nt], acc[mt][nt], 0, 0, 0);
        }
    }

    int hd = blockIdx.x * 4 + wid;
    int cbase = col0 + wid * 32 + li;
    float as0 = a_s[cbase];
    float as1 = a_s[cbase + 16];
    float ad0 = a_d[cbase];
    float ad1 = a_d[cbase + 16];

#pragma unroll
    for (int mt = 0; mt < 2; mt++) {
        int row = row0 + mt * 16 + lq * 4;
#pragma unroll
        for (int r = 0; r < 4; r++) {
            float v0 = acc[mt][0][r];
            float v1 = acc[mt][1][r];
            unsigned int pk = __builtin_amdgcn_cvt_pk_fp8_f32(v0, v1, 0, false);
            Cf8[(size_t)(row + r) * CDIM + cbase]      = (uchar_t)(pk & 0xff);
            Cf8[(size_t)(row + r) * CDIM + cbase + 16] = (uchar_t)((pk >> 8) & 0xff);
            float ps = v0 * as0 + v1 * as1;
            float pd = v0 * ad0 + v1 * ad1;
#pragma unroll
            for (int d = 1; d < 16; d <<= 1) {
                ps += __shfl_xor(ps, d);
                pd += __shfl_xor(pd, d);
            }
            if (li == 0) {
                esrc[(size_t)(row + r) * NHEAD + hd] = ps;
                edst[(size_t)(row + r) * NHEAD + hd] = pd;
            }
        }
    }
}

// ---------------------------------------------------------------------------
// fp32 tiled GEMM (tiny matmuls), batched.
// ---------------------------------------------------------------------------
__global__ __launch_bounds__(256) void gemm64(
    const float* __restrict__ A, const float* __restrict__ A2,
    const float* __restrict__ B, const float* __restrict__ bias,
    float* __restrict__ C, int M, int K, int Nf, int doRelu,
    int sA, int sB, int sC)
{
    __shared__ float As[16][64];
    __shared__ float Bs[16][64];
    A += (size_t)blockIdx.z * sA;
    B += (size_t)blockIdx.z * sB;
    C += (size_t)blockIdx.z * sC;
    int tid = threadIdx.x;
    int tx = tid & 15, ty = tid >> 4;
    int row0 = blockIdx.y * 64, col0 = blockIdx.x * 64;
    int ar = tid >> 2;
    int ac = (tid & 3) * 4;

    float acc[4][4] = {};

    for (int k0 = 0; k0 < K; k0 += 16) {
        int arow = row0 + ar;
        float4 av = make_float4(0.f, 0.f, 0.f, 0.f);
        if (arow < M) {
            av = *(const float4*)(A + (size_t)arow * K + k0 + ac);
            if (A2) {
                float4 a2 = *(const float4*)(A2 + (size_t)arow * K + k0 + ac);
                av.x += a2.x; av.y += a2.y; av.z += a2.z; av.w += a2.w;
            }
        }
        As[ac + 0][ar] = av.x;
        As[ac + 1][ar] = av.y;
        As[ac + 2][ar] = av.z;
        As[ac + 3][ar] = av.w;
        float4 bv = *(const float4*)(B + (size_t)(k0 + (tid >> 4)) * Nf + col0 + (tid & 15) * 4);
        *(float4*)&Bs[tid >> 4][(tid & 15) * 4] = bv;
        __syncthreads();
#pragma unroll
        for (int kk = 0; kk < 16; kk++) {
            float4 a = *(const float4*)&As[kk][ty * 4];
            float4 b = *(const float4*)&Bs[kk][tx * 4];
            acc[0][0] += a.x * b.x; acc[0][1] += a.x * b.y; acc[0][2] += a.x * b.z; acc[0][3] += a.x * b.w;
            acc[1][0] += a.y * b.x; acc[1][1] += a.y * b.y; acc[1][2] += a.y * b.z; acc[1][3] += a.y * b.w;
            acc[2][0] += a.z * b.x; acc[2][1] += a.z * b.y; acc[2][2] += a.z * b.z; acc[2][3] += a.z * b.w;
            acc[3][0] += a.w * b.x; acc[3][1] += a.w * b.y; acc[3][2] += a.w * b.z; acc[3][3] += a.w * b.w;
        }
        __syncthreads();
    }

    float4 bv = make_float4(0.f, 0.f, 0.f, 0.f);
    if (bias) bv = *(const float4*)(bias + col0 + tx * 4);
#pragma unroll
    for (int i = 0; i < 4; i++) {
        int r = row0 + ty * 4 + i;
        if (r < M) {
            float4 o;
            o.x = acc[i][0] + bv.x;
            o.y = acc[i][1] + bv.y;
            o.z = acc[i][2] + bv.z;
            o.w = acc[i][3] + bv.w;
            if (doRelu) {
                o.x = fmaxf(o.x, 0.f); o.y = fmaxf(o.y, 0.f);
                o.z = fmaxf(o.z, 0.f); o.w = fmaxf(o.w, 0.f);
            }
            *(float4*)(C + (size_t)r * Nf + col0 + tx * 4) = o;
        }
    }
}

// ---------------------------------------------------------------------------
// Prep kernels
// ---------------------------------------------------------------------------
// combined convert of x and temb
__global__ void cvt_bf16_2(const float* __restrict__ a, ushort_t* __restrict__ oa, int na,
                           const float* __restrict__ b, ushort_t* __restrict__ ob, int nb)
{
    int i = blockIdx.x * blockDim.x + threadIdx.x;
    if (i < na) oa[i] = f2bf(a[i]);
    else if (i - na < nb) ob[i - na] = f2bf(b[i - na]);
}

__global__ __launch_bounds__(256) void transpose_cast(
    const float* __restrict__ in, int K, int Nn,
    ushort_t* __restrict__ out, int ostride, int koff,
    int inBatchStride, int outBatchStride)
{
    __shared__ float tile[32][33];
    in  += (size_t)blockIdx.z * inBatchStride;
    out += (size_t)blockIdx.z * outBatchStride;
    int k0 = blockIdx.y * 32, n0 = blockIdx.x * 32;
    int tx = threadIdx.x & 31, ty = threadIdx.x >> 5;
#pragma unroll
    for (int j = 0; j < 4; j++)
        tile[ty + j * 8][tx] = in[(size_t)(k0 + ty + j * 8) * Nn + n0 + tx];
    __syncthreads();
#pragma unroll
    for (int j = 0; j < 4; j++) {
        int n = n0 + ty + j * 8;
        out[(size_t)n * ostride + koff + k0 + tx] = f2bf(tile[tx][ty + j * 8]);
    }
}

// Wqk[l][j][d] = (1/16) * sum_c Wq[l][d][c] * kbuf[l][j][c]
__global__ __launch_bounds__(256) void wqk_build(
    const float* __restrict__ Wq, const float* __restrict__ kbufs,
    float* __restrict__ wqk)
{
    int j = blockIdx.x, l = blockIdx.y;
    int d = threadIdx.x;
    __shared__ float kk[CDIM];
    kk[d] = kbufs[((size_t)l * MSLOT + j) * CDIM + d];
    __syncthreads();
    const float* wrow = Wq + ((size_t)l * CDIM + d) * CDIM;
    float acc = 0.f;
#pragma unroll 4
    for (int c = 0; c < CDIM; c++) acc += wrow[c] * kk[c];
    wqk[((size_t)l * MSLOT + j) * CDIM + d] = acc * 0.0625f;
}

// ---------------------------------------------------------------------------
// CSR construction
// ---------------------------------------------------------------------------
__global__ void count_deg(const int* __restrict__ dst, int* __restrict__ deg, int ne)
{
    int e = blockIdx.x * blockDim.x + threadIdx.x;
    if (e < ne) atomicAdd(&deg[dst[e]], 1);
}

// single-pass exclusive scan: thread t owns 20 contiguous elements
__global__ __launch_bounds__(1024) void scan_kernel(const int* __restrict__ deg,
                                                    int* __restrict__ offs, int n)
{
    __shared__ int swt[16];
    int tid = threadIdx.x, lane = tid & 63, wid = tid >> 6;
    int base = tid * 20;
    int v[20];
    int s = 0;
#pragma unroll
    for (int i = 0; i < 20; i++) {
        int d = (base + i < n) ? deg[base + i] : 0;
        v[i] = d; s += d;
    }
    int x = s;
#pragma unroll
    for (int d = 1; d < 64; d <<= 1) {
        int t = __shfl_up(x, d);
        if (lane >= d) x += t;
    }
    if (lane == 63) swt[wid] = x;
    __syncthreads();
    if (wid == 0) {
        int w = (lane < 16) ? swt[lane] : 0;
#pragma unroll
        for (int d = 1; d < 16; d <<= 1) {
            int t = __shfl_up(w, d);
            if (lane >= d) w += t;
        }
        if (lane < 16) swt[lane] = w;
    }
    __syncthreads();
    int wbase = (wid == 0) ? 0 : swt[wid - 1];
    int run = wbase + x - s;
#pragma unroll
    for (int i = 0; i < 20; i++) {
        if (base + i < n) offs[base + i] = run;
        run += v[i];
    }
}

__global__ void fill_csr(const int* __restrict__ src, const int* __restrict__ dst,
                         const int* __restrict__ offs, int* __restrict__ cursor,
                         int* __restrict__ csr_src, int ne)
{
    int e = blockIdx.x * blockDim.x + threadIdx.x;
    if (e < ne) {
        int d = dst[e];
        int p = atomicAdd(&cursor[d], 1);
        csr_src[offs[d] + p] = src[e];
    }
}

// ---------------------------------------------------------------------------
// Fully fused GAT + cross-attn. h in fp8 e4m3; prefetched h-gathers.
// out = relu(gat + softmax(gat.Wqk).v + node_in)
// ---------------------------------------------------------------------------
__global__ __launch_bounds__(256) void gat_agg_fused(
    const uchar_t* __restrict__ h, const float* __restrict__ esrc, const float* __restrict__ edst,
    const int* __restrict__ offs, const int* __restrict__ deg, const int* __restrict__ csr_src,
    const float* __restrict__ wqk, const float* __restrict__ vbuf,
    const ushort_t* __restrict__ node_in,
    ushort_t* __restrict__ node_out, int n)
{
    int tid = threadIdx.x;
    int lane = tid & 63;
    int wslot = tid >> 6;
    int node = blockIdx.x * 4 + wslot;
    int start = offs[node], cnt = deg[node];
    int chead = lane >> 3;

    ushort4 c4 = *(const ushort4*)(node_in + (size_t)node * CDIM + lane * 4);

    float4 gat4;
    if (cnt <= 64) {
        int eh = lane >> 3, hh = lane & 7;
        float edl = edst[(size_t)node * NHEAD + hh];
        int sl = (lane < cnt) ? csr_src[start + lane] : 0;
        int nit = (cnt + 7) >> 3;
        int npf = nit < 4 ? nit : 4;

        unsigned int hw[4][8];
#pragma unroll
        for (int rr = 0; rr < 4; rr++) {
            if (rr < npf) {
#pragma unroll
                for (int k = 0; k < 8; k++) {
                    int sv = __shfl(sl, rr * 8 + k);
                    hw[rr][k] = *(const unsigned int*)(h + (size_t)sv * CDIM + lane * 4);
                }
            }
        }

        float lg[8], w8[8];
        float m = -3.0e38f;
#pragma unroll
        for (int it = 0; it < 8; it++) {
            float v = -3.0e38f;
            if (it < nit) {
                int e = it * 8 + eh;
                int se = __shfl(sl, e);
                if (e < cnt) {
                    float t = esrc[(size_t)se * NHEAD + hh] + edl;
                    v = t > 0.f ? t : 0.2f * t;
                }
            }
            lg[it] = v;
            m = fmaxf(m, v);
        }
        m = fmaxf(m, __shfl_xor(m, 8));
        m = fmaxf(m, __shfl_xor(m, 16));
        m = fmaxf(m, __shfl_xor(m, 32));
        float den = 0.f;
#pragma unroll
        for (int it = 0; it < 8; it++) {
            float w = 0.f;
            if (it < nit) {
                int e = it * 8 + eh;
                if (e < cnt) w = __expf(lg[it] - m);
            }
            w8[it] = w;
            den += w;
        }
        den += __shfl_xor(den, 8);
        den += __shfl_xor(den, 16);
        den += __shfl_xor(den, 32);
        float inv = 1.f / (den + 1e-16f);
        float invc = __shfl(inv, chead);

        float4 acc = make_float4(0.f, 0.f, 0.f, 0.f);
#pragma unroll
        for (int rr = 0; rr < 4; rr++) {
            if (rr < npf) {
                float av[8];
#pragma unroll
                for (int k = 0; k < 8; k++)
                    av[k] = __shfl(w8[rr], (k << 3) | chead);
#pragma unroll
                for (int k = 0; k < 8; k++) {
                    floatx2 lo = __builtin_amdgcn_cvt_pk_f32_fp8((int)hw[rr][k], false);
                    floatx2 hi = __builtin_amdgcn_cvt_pk_f32_fp8((int)hw[rr][k], true);
                    acc.x += av[k] * lo.x;
                    acc.y += av[k] * lo.y;
                    acc.z += av[k] * hi.x;
                    acc.w += av[k] * hi.y;
                }
            }
        }
        for (int rr = 4; rr < nit; rr++) {
            int sv[8]; float av[8];
#pragma unroll
            for (int k = 0; k < 8; k++) {
                sv[k] = __shfl(sl, rr * 8 + k);
                av[k] = __shfl(w8[rr], (k << 3) | chead);
            }
#pragma unroll
            for (int k = 0; k < 8; k++) {
                unsigned int hwv = *(const unsigned int*)(h + (size_t)sv[k] * CDIM + lane * 4);
                floatx2 lo = __builtin_amdgcn_cvt_pk_f32_fp8((int)hwv, false);
                floatx2 hi = __builtin_amdgcn_cvt_pk_f32_fp8((int)hwv, true);
                acc.x += av[k] * lo.x;
                acc.y += av[k] * lo.y;
                acc.z += av[k] * hi.x;
                acc.w += av[k] * hi.y;
            }
        }
        gat4.x = fmaxf(acc.x * invc, 0.f);
        gat4.y = fmaxf(acc.y * invc, 0.f);
        gat4.z = fmaxf(acc.z * invc, 0.f);
        gat4.w = fmaxf(acc.w * invc, 0.f);
    } else {
        int hh = lane & 7;
        float edl = edst[(size_t)node * NHEAD + hh];
        float m = -3.0e38f;
        int i8 = lane >> 3;
        for (int i = 0; i < cnt; i += 8) {
            int ii = i + i8;
            if (ii < cnt) {
                int s = csr_src[start + ii];
                float lgv = esrc[(size_t)s * NHEAD + hh] + edl;
                lgv = lgv > 0.f ? lgv : 0.2f * lgv;
                m = fmaxf(m, lgv);
            }
        }
        m = fmaxf(m, __shfl_xor(m, 8));
        m = fmaxf(m, __shfl_xor(m, 16));
        m = fmaxf(m, __shfl_xor(m, 32));
        float4 acc = make_float4(0.f, 0.f, 0.f, 0.f);
        float den = 0.f;
        for (int i = 0; i < cnt; i++) {
            int s = csr_src[start + i];
            float lgv = esrc[(size_t)s * NHEAD + hh] + edl;
            lgv = lgv > 0.f ? lgv : 0.2f * lgv;
            float w = __expf(lgv - m);
            den += w;
            float wc = __shfl(w, chead);
            unsigned int hwv = *(const unsigned int*)(h + (size_t)s * CDIM + lane * 4);
            floatx2 lo = __builtin_amdgcn_cvt_pk_f32_fp8((int)hwv, false);
            floatx2 hi = __builtin_amdgcn_cvt_pk_f32_fp8((int)hwv, true);
            acc.x += wc * lo.x; acc.y += wc * lo.y;
            acc.z += wc * hi.x; acc.w += wc * hi.y;
        }
        float dc = __shfl(den, chead) + 1e-16f;
        float inv = 1.f / dc;
        gat4.x = fmaxf(acc.x * inv, 0.f);
        gat4.y = fmaxf(acc.y * inv, 0.f);
        gat4.z = fmaxf(acc.z * inv, 0.f);
        gat4.w = fmaxf(acc.w * inv, 0.f);
    }

    float s[MSLOT];
#pragma unroll
    for (int j = 0; j < MSLOT; j++) {
        float4 w4 = *(const float4*)(wqk + j * CDIM + lane * 4);
        s[j] = gat4.x * w4.x + gat4.y * w4.y + gat4.z * w4.z + gat4.w * w4.w;
    }
#pragma unroll
    for (int d = 1; d < 64; d <<= 1) {
#pragma unroll
        for (int j = 0; j < MSLOT; j++) s[j] += __shfl_xor(s[j], d);
    }
    float m = s[0];
#pragma unroll
    for (int j = 1; j < MSLOT; j++) m = fmaxf(m, s[j]);
    float sum = 0.f;
#pragma unroll
    for (int j = 0; j < MSLOT; j++) { s[j] = __expf(s[j] - m); sum += s[j]; }
    float inv = 1.f / sum;

    float4 o;
    o.x = gat4.x + bf2f(c4.x); o.y = gat4.y + bf2f(c4.y);
    o.z = gat4.z + bf2f(c4.z); o.w = gat4.w + bf2f(c4.w);
#pragma unroll
    for (int j = 0; j < MSLOT; j++) {
        float p = s[j] * inv;
        float4 v4 = *(const float4*)(vbuf + j * CDIM + lane * 4);
        o.x += p * v4.x; o.y += p * v4.y; o.z += p * v4.z; o.w += p * v4.w;
    }
    o.x = fmaxf(o.x, 0.f); o.y = fmaxf(o.y, 0.f); o.z = fmaxf(o.z, 0.f); o.w = fmaxf(o.w, 0.f);
    ushort4 ob;
    ob.x = f2bf(o.x); ob.y = f2bf(o.y); ob.z = f2bf(o.z); ob.w = f2bf(o.w);
    *(ushort4*)(node_out + (size_t)node * CDIM + lane * 4) = ob;
}

// ---------------------------------------------------------------------------
// Pooling stage 1: per-block column partial sums. NO atomics.
// Block b owns rows [b*100, b*100+100). Wave w handles rows w, w+4, ...
// Each lane owns 4 channels. Cross-wave reduce via LDS, plain store of
// partial[b][256].
__global__ __launch_bounds__(256) void col_part(const ushort_t* __restrict__ node,
                                                float* __restrict__ partial, int n)
{
    __shared__ __align__(16) float sred[4][CDIM];
    int tid = threadIdx.x;
    int lane = tid & 63, w = tid >> 6;
    int cg = lane * 4;
    int rows = (n + NBPOOL - 1) / NBPOOL;
    int r0 = blockIdx.x * rows;
    int r1 = r0 + rows; if (r1 > n) r1 = n;
    float4 acc = make_float4(0.f, 0.f, 0.f, 0.f);
    for (int r = r0 + w; r < r1; r += 4) {
        ushort4 v = *(const ushort4*)(node + (size_t)r * CDIM + cg);
        acc.x += bf2f(v.x); acc.y += bf2f(v.y); acc.z += bf2f(v.z); acc.w += bf2f(v.w);
    }
    *(float4*)&sred[w][cg] = acc;
    __syncthreads();
    // thread tid owns channel tid
    float s = sred[0][tid] + sred[1][tid] + sred[2][tid] + sred[3][tid];
    partial[(size_t)blockIdx.x * CDIM + tid] = s;
}

// Pooling stage 2 + final projection. 256 threads.
__global__ __launch_bounds__(256) void finalize(
    const float* __restrict__ partial, const float* __restrict__ mem,
    const float* __restrict__ Wc, const float* __restrict__ bc,
    float* __restrict__ out)
{
    __shared__ float fv[CDIM + MDIM];
    __shared__ float r0s[4], r1s[4];
    int tid = threadIdx.x;
    if (tid < CDIM) {
        float s = 0.f;
        for (int b = 0; b < NBPOOL; b++) s += partial[(size_t)b * CDIM + tid];
        fv[tid] = s * (1.0f / (float)N_NODES);
    } else {
        int i = tid - CDIM;   // 0..127? only 0..? tid in [256,256) none; handle below
    }
    if (tid < MDIM) {
        float s = 0.f;
        for (int r = 0; r < MSLOT; r++) s += mem[r * MDIM + tid];
        fv[CDIM + tid] = s * (1.0f / (float)MSLOT);
    }
    __syncthreads();
    float a0 = 0.f, a1 = 0.f;
    for (int i = tid; i < CDIM + MDIM; i += 256) {
        a0 += fv[i] * Wc[i * NCLS + 0];
        a1 += fv[i] * Wc[i * NCLS + 1];
    }
#pragma unroll
    for (int d = 1; d < 64; d <<= 1) { a0 += __shfl_xor(a0, d); a1 += __shfl_xor(a1, d); }
    if ((tid & 63) == 0) { r0s[tid >> 6] = a0; r1s[tid >> 6] = a1; }
    __syncthreads();
    if (tid == 0) {
        out[0] = r0s[0] + r0s[1] + r0s[2] + r0s[3] + bc[0];
        out[1] = r1s[0] + r1s[1] + r1s[2] + r1s[3] + bc[1];
    }
}

// ---------------------------------------------------------------------------
extern "C" void kernel_launch(void* const* d_in, const int* in_sizes, int n_in,
                              void* d_out, int out_size, void* d_ws, size_t ws_size,
                              hipStream_t stream)
{
    const float* x    = (const float*)d_in[0];
    const int*   ei   = (const int*)d_in[1];
    const float* temb = (const float*)d_in[2];
    const float* Wi   = (const float*)d_in[3];
    const float* bi   = (const float*)d_in[4];
    const float* Wg   = (const float*)d_in[5];
    const float* a_s  = (const float*)d_in[6];
    const float* a_d  = (const float*)d_in[7];
    const float* Wt   = (const float*)d_in[8];
    const float* Wq   = (const float*)d_in[9];
    const float* Wk   = (const float*)d_in[10];
    const float* Wv   = (const float*)d_in[11];
    const float* mem  = (const float*)d_in[12];
    const float* Wc   = (const float*)d_in[13];
    const float* bc   = (const float*)d_in[14];
    float* out = (float*)d_out;
    char* ws = (char*)d_ws;

    const size_t NCB_BYTES = (size_t)N_NODES * CDIM * 2;
    size_t off = 0;
    ushort_t* nodeA  = (ushort_t*)(ws + off); off += NCB_BYTES;
    ushort_t* nodeB  = (ushort_t*)(ws + off); off += NCB_BYTES;
    uchar_t*  hf8    = (uchar_t*)(ws + off);  off += (size_t)N_NODES * CDIM;   // 5.12 MB
    ushort_t* xbf    = (ushort_t*)(ws + off); off += (size_t)N_NODES * FEAT * 2;
    ushort_t* tembbf = (ushort_t*)(ws + off); off += (size_t)N_NODES * TDIM * 2;
    float* esrc   = (float*)(ws + off); off += (size_t)N_NODES * NHEAD * 4;
    float* edst   = (float*)(ws + off); off += (size_t)N_NODES * NHEAD * 4;
    float* kbufs  = (float*)(ws + off); off += (size_t)NLAYER * MSLOT * CDIM * 4;
    float* vbufs  = (float*)(ws + off); off += (size_t)NLAYER * MSLOT * CDIM * 4;
    float* wqkL   = (float*)(ws + off); off += (size_t)NLAYER * MSLOT * CDIM * 4;
    float* Wtp    = (float*)(ws + off); off += (size_t)NLAYER * TDIM * CDIM * 4;
    ushort_t* Bt_i = (ushort_t*)(ws + off); off += (size_t)CDIM * FEAT * 2;
    ushort_t* Bt_h = (ushort_t*)(ws + off); off += (size_t)NLAYER * CDIM * (CDIM + TDIM) * 2;
    float* partial = (float*)(ws + off); off += (size_t)NBPOOL * CDIM * 4;
    size_t zero_base = off;
    int* deg      = (int*)(ws + off);   off += N_NODES * 4;
    int* cursor   = (int*)(ws + off);   off += N_NODES * 4;
    size_t zero_len = off - zero_base;
    int* offs     = (int*)(ws + off);   off += (N_NODES + 4) * 4;
    int* csr_src  = (int*)(ws + off);   off += (size_t)E_EDGES * 4;

    const int* srcIdx = ei;
    const int* dstIdx = ei + E_EDGES;

    hipMemsetAsync(ws + zero_base, 0, zero_len, stream);

    // ---- prep ----
    cvt_bf16_2<<<(N_NODES * (FEAT + TDIM) + 255) / 256, 256, 0, stream>>>(
        x, xbf, N_NODES * FEAT, temb, tembbf, N_NODES * TDIM);
    gemm64<<<dim3(4, 1, NLAYER), 256, 0, stream>>>(Wt, nullptr, Wg, nullptr, Wtp,
        TDIM, CDIM, CDIM, 0, TDIM * CDIM, CDIM * CDIM, TDIM * CDIM);
    transpose_cast<<<dim3(CDIM / 32, FEAT / 32, 1), 256, 0, stream>>>(
        Wi, FEAT, CDIM, Bt_i, FEAT, 0, 0, 0);
    transpose_cast<<<dim3(CDIM / 32, CDIM / 32, NLAYER), 256, 0, stream>>>(
        Wg, CDIM, CDIM, Bt_h, CDIM + TDIM, 0, CDIM * CDIM, CDIM * (CDIM + TDIM));
    transpose_cast<<<dim3(CDIM / 32, TDIM / 32, NLAYER), 256, 0, stream>>>(
        Wtp, TDIM, CDIM, Bt_h, CDIM + TDIM, CDIM, TDIM * CDIM, CDIM * (CDIM + TDIM));
    gemm64<<<dim3(4, 1, NLAYER), 256, 0, stream>>>(mem, nullptr, Wk, nullptr, kbufs,
        MSLOT, MDIM, CDIM, 0, 0, MDIM * CDIM, MSLOT * CDIM);
    gemm64<<<dim3(4, 1, NLAYER), 256, 0, stream>>>(mem, nullptr, Wv, nullptr, vbufs,
        MSLOT, MDIM, CDIM, 0, 0, MDIM * CDIM, MSLOT * CDIM);
    wqk_build<<<dim3(MSLOT, NLAYER), 256, 0, stream>>>(Wq, kbufs, wqkL);

    // ---- CSR ----
    count_deg<<<(E_EDGES + 255) / 256, 256, 0, stream>>>(dstIdx, deg, E_EDGES);
    scan_kernel<<<1, 1024, 0, stream>>>(deg, offs, N_NODES);
    fill_csr<<<(E_EDGES + 255) / 256, 256, 0, stream>>>(srcIdx, dstIdx, offs, cursor, csr_src, E_EDGES);

    dim3 mfmaGrid(2, N_NODES / 32);   // 2 x 625 = 1250 blocks
    int nodeBlocks = N_NODES / 4;

    // node = relu(x @ Wi + bi) -> nodeA (bf16)
    gemm_mfma<<<mfmaGrid, 256, 0, stream>>>(xbf, FEAT, FEAT, nullptr, 0, FEAT,
                                            Bt_i, bi, nodeA, 1);

    ushort_t* cur = nodeA;
    ushort_t* alt = nodeB;
    for (int l = 0; l < NLAYER; l++) {
        gemm_h<<<mfmaGrid, 256, 0, stream>>>(cur, CDIM, CDIM, tembbf, TDIM, CDIM + TDIM,
                                             Bt_h + (size_t)l * CDIM * (CDIM + TDIM),
                                             a_s + (size_t)l * CDIM, a_d + (size_t)l * CDIM,
                                             hf8, esrc, edst);
        gat_agg_fused<<<nodeBlocks, 256, 0, stream>>>(hf8, esrc, edst, offs, deg, csr_src,
                                                      wqkL + (size_t)l * MSLOT * CDIM,
                                                      vbufs + (size_t)l * MSLOT * CDIM,
                                                      cur, alt, N_NODES);
        ushort_t* t = cur; cur = alt; alt = t;
    }

    col_part<<<NBPOOL, 256, 0, stream>>>(cur, partial, N_NODES);
    finalize<<<1, 256, 0, stream>>>(partial, mem, Wc, bc, out);
}

// Round 11
// 459.762 us; speedup vs baseline: 1.1454x; 1.0405x over previous
//
#include <hip/hip_runtime.h>
#include <hip/hip_bf16.h>

#define N_NODES 20000
#define E_EDGES 320000
#define FEAT 128
#define CDIM 256
#define NHEAD 8
#define HDIM 32
#define NLAYER 5
#define TDIM 64
#define MSLOT 10
#define MDIM 128
#define NCLS 2
#define NBPOOL 200

typedef unsigned short ushort_t;
typedef unsigned char uchar_t;
typedef short short8 __attribute__((ext_vector_type(8)));
typedef float floatx4 __attribute__((ext_vector_type(4)));
typedef float floatx2 __attribute__((ext_vector_type(2)));

__device__ __forceinline__ ushort_t f2bf(float f) {
    union { float f; unsigned int u; } t; t.f = f;
    unsigned int r = (t.u + 0x7FFF + ((t.u >> 16) & 1)) >> 16;
    return (ushort_t)r;
}
__device__ __forceinline__ float bf2f(ushort_t u) {
    union { float f; unsigned int u; } t; t.u = ((unsigned int)u) << 16;
    return t.f;
}

// ---------------------------------------------------------------------------
// bf16 MFMA GEMM, BM=32, BN=128, BK=64. grid (2, M/32) = 1250 blocks.
// ---------------------------------------------------------------------------
__global__ __launch_bounds__(256) void gemm_mfma(
    const ushort_t* __restrict__ A1, int lda1, int K1,
    const ushort_t* __restrict__ A2, int lda2, int Ktot,
    const ushort_t* __restrict__ Bt,
    const float* __restrict__ bias,
    ushort_t* Cbf, int doRelu)
{
    __shared__ __align__(16) ushort_t smemA[32 * 64];
    __shared__ __align__(16) ushort_t smemB[128 * 64];
    int tid = threadIdx.x;
    int lane = tid & 63, wid = tid >> 6;
    int li = lane & 15, lq = lane >> 4;
    int row0 = blockIdx.y * 32;
    int col0 = blockIdx.x * 128;

    floatx4 acc[2][2];
#pragma unroll
    for (int a = 0; a < 2; a++)
#pragma unroll
        for (int b = 0; b < 2; b++) acc[a][b] = {0.f, 0.f, 0.f, 0.f};

    int ar = tid >> 3, ac = tid & 7;
    int agc = (ac - (ar >> 1)) & 7;

    for (int k0 = 0; k0 < Ktot; k0 += 64) {
        __syncthreads();
        const ushort_t* Ab; int lda;
        if (k0 < K1) { Ab = A1 + k0; lda = lda1; }
        else         { Ab = A2 + (k0 - K1); lda = lda2; }
        {
            const void* g = (const void*)(Ab + (size_t)(row0 + ar) * lda + agc * 8);
            __builtin_amdgcn_global_load_lds(
                (const __attribute__((address_space(1))) void*)g,
                (__attribute__((address_space(3))) void*)&smemA[wid * 512], 16, 0, 0);
        }
#pragma unroll
        for (int j = 0; j < 4; j++) {
            int slot = j * 256 + tid;
            int n = slot >> 3, c = slot & 7;
            int gc = (c - (n >> 1)) & 7;
            const void* g = (const void*)(Bt + (size_t)(col0 + n) * Ktot + k0 + gc * 8);
            __builtin_amdgcn_global_load_lds(
                (const __attribute__((address_space(1))) void*)g,
                (__attribute__((address_space(3))) void*)&smemB[(j * 256 + wid * 64) * 8], 16, 0, 0);
        }
        __syncthreads();

#pragma unroll
        for (int ks = 0; ks < 2; ks++) {
            short8 af[2], bfr[2];
#pragma unroll
            for (int mt = 0; mt < 2; mt++) {
                int m = mt * 16 + li;
                int sw = ((ks * 4 + lq) + (m >> 1)) & 7;
                af[mt] = *(const short8*)&smemA[m * 64 + sw * 8];
            }
#pragma unroll
            for (int nt = 0; nt < 2; nt++) {
                int nl = wid * 32 + nt * 16 + li;
                int sw = ((ks * 4 + lq) + (nl >> 1)) & 7;
                bfr[nt] = *(const short8*)&smemB[nl * 64 + sw * 8];
            }
#pragma unroll
            for (int mt = 0; mt < 2; mt++)
#pragma unroll
                for (int nt = 0; nt < 2; nt++)
                    acc[mt][nt] = __builtin_amdgcn_mfma_f32_16x16x32_bf16(af[mt], bfr[nt], acc[mt][nt], 0, 0, 0);
        }
    }

#pragma unroll
    for (int mt = 0; mt < 2; mt++) {
        int row = row0 + mt * 16 + lq * 4;
#pragma unroll
        for (int nt = 0; nt < 2; nt++) {
            int col = col0 + wid * 32 + nt * 16 + li;
            float bv = bias ? bias[col] : 0.f;
#pragma unroll
            for (int r = 0; r < 4; r++) {
                float v = acc[mt][nt][r] + bv;
                if (doRelu) v = fmaxf(v, 0.f);
                Cbf[(size_t)(row + r) * CDIM + col] = f2bf(v);
            }
        }
    }
}

// h-GEMM (BM=32,BN=128,BK=64): writes h in fp8 e4m3 + fused head logits.
__global__ __launch_bounds__(256) void gemm_h(
    const ushort_t* __restrict__ A1, int lda1, int K1,
    const ushort_t* __restrict__ A2, int lda2, int Ktot,
    const ushort_t* __restrict__ Bt,
    const float* __restrict__ a_s, const float* __restrict__ a_d,
    uchar_t* __restrict__ Cf8,
    float* __restrict__ esrc, float* __restrict__ edst)
{
    __shared__ __align__(16) ushort_t smemA[32 * 64];
    __shared__ __align__(16) ushort_t smemB[128 * 64];
    int tid = threadIdx.x;
    int lane = tid & 63, wid = tid >> 6;
    int li = lane & 15, lq = lane >> 4;
    int row0 = blockIdx.y * 32;
    int col0 = blockIdx.x * 128;

    floatx4 acc[2][2];
#pragma unroll
    for (int a = 0; a < 2; a++)
#pragma unroll
        for (int b = 0; b < 2; b++) acc[a][b] = {0.f, 0.f, 0.f, 0.f};

    int ar = tid >> 3, ac = tid & 7;
    int agc = (ac - (ar >> 1)) & 7;

    for (int k0 = 0; k0 < Ktot; k0 += 64) {
        __syncthreads();
        const ushort_t* Ab; int lda;
        if (k0 < K1) { Ab = A1 + k0; lda = lda1; }
        else         { Ab = A2 + (k0 - K1); lda = lda2; }
        {
            const void* g = (const void*)(Ab + (size_t)(row0 + ar) * lda + agc * 8);
            __builtin_amdgcn_global_load_lds(
                (const __attribute__((address_space(1))) void*)g,
                (__attribute__((address_space(3))) void*)&smemA[wid * 512], 16, 0, 0);
        }
#pragma unroll
        for (int j = 0; j < 4; j++) {
            int slot = j * 256 + tid;
            int n = slot >> 3, c = slot & 7;
            int gc = (c - (n >> 1)) & 7;
            const void* g = (const void*)(Bt + (size_t)(col0 + n) * Ktot + k0 + gc * 8);
            __builtin_amdgcn_global_load_lds(
                (const __attribute__((address_space(1))) void*)g,
                (__attribute__((address_space(3))) void*)&smemB[(j * 256 + wid * 64) * 8], 16, 0, 0);
        }
        __syncthreads();

#pragma unroll
        for (int ks = 0; ks < 2; ks++) {
            short8 af[2], bfr[2];
#pragma unroll
            for (int mt = 0; mt < 2; mt++) {
                int m = mt * 16 + li;
                int sw = ((ks * 4 + lq) + (m >> 1)) & 7;
                af[mt] = *(const short8*)&smemA[m * 64 + sw * 8];
            }
#pragma unroll
            for (int nt = 0; nt < 2; nt++) {
                int nl = wid * 32 + nt * 16 + li;
                int sw = ((ks * 4 + lq) + (nl >> 1)) & 7;
                bfr[nt] = *(const short8*)&smemB[nl * 64 + sw * 8];
            }
#pragma unroll
            for (int mt = 0; mt < 2; mt++)
#pragma unroll
                for (int nt = 0; nt < 2; nt++)
                    acc[mt][nt] = __builtin_amdgcn_mfma_f32_16x16x32_bf16(af[mt], bfr[nt], acc[mt][nt], 0, 0, 0);
        }
    }

    int hd = blockIdx.x * 4 + wid;
    int cbase = col0 + wid * 32 + li;
    float as0 = a_s[cbase];
    float as1 = a_s[cbase + 16];
    float ad0 = a_d[cbase];
    float ad1 = a_d[cbase + 16];

#pragma unroll
    for (int mt = 0; mt < 2; mt++) {
        int row = row0 + mt * 16 + lq * 4;
#pragma unroll
        for (int r = 0; r < 4; r++) {
            float v0 = acc[mt][0][r];
            float v1 = acc[mt][1][r];
            unsigned int pk = __builtin_amdgcn_cvt_pk_fp8_f32(v0, v1, 0, false);
            Cf8[(size_t)(row + r) * CDIM + cbase]      = (uchar_t)(pk & 0xff);
            Cf8[(size_t)(row + r) * CDIM + cbase + 16] = (uchar_t)((pk >> 8) & 0xff);
            float ps = v0 * as0 + v1 * as1;
            float pd = v0 * ad0 + v1 * ad1;
#pragma unroll
            for (int d = 1; d < 16; d <<= 1) {
                ps += __shfl_xor(ps, d);
                pd += __shfl_xor(pd, d);
            }
            if (li == 0) {
                esrc[(size_t)(row + r) * NHEAD + hd] = ps;
                edst[(size_t)(row + r) * NHEAD + hd] = pd;
            }
        }
    }
}

// ---------------------------------------------------------------------------
// fp32 tiled GEMM (tiny matmuls), batched.
// ---------------------------------------------------------------------------
__global__ __launch_bounds__(256) void gemm64(
    const float* __restrict__ A, const float* __restrict__ A2,
    const float* __restrict__ B, const float* __restrict__ bias,
    float* __restrict__ C, int M, int K, int Nf, int doRelu,
    int sA, int sB, int sC)
{
    __shared__ float As[16][64];
    __shared__ float Bs[16][64];
    A += (size_t)blockIdx.z * sA;
    B += (size_t)blockIdx.z * sB;
    C += (size_t)blockIdx.z * sC;
    int tid = threadIdx.x;
    int tx = tid & 15, ty = tid >> 4;
    int row0 = blockIdx.y * 64, col0 = blockIdx.x * 64;
    int ar = tid >> 2;
    int ac = (tid & 3) * 4;

    float acc[4][4] = {};

    for (int k0 = 0; k0 < K; k0 += 16) {
        int arow = row0 + ar;
        float4 av = make_float4(0.f, 0.f, 0.f, 0.f);
        if (arow < M) {
            av = *(const float4*)(A + (size_t)arow * K + k0 + ac);
            if (A2) {
                float4 a2 = *(const float4*)(A2 + (size_t)arow * K + k0 + ac);
                av.x += a2.x; av.y += a2.y; av.z += a2.z; av.w += a2.w;
            }
        }
        As[ac + 0][ar] = av.x;
        As[ac + 1][ar] = av.y;
        As[ac + 2][ar] = av.z;
        As[ac + 3][ar] = av.w;
        float4 bv = *(const float4*)(B + (size_t)(k0 + (tid >> 4)) * Nf + col0 + (tid & 15) * 4);
        *(float4*)&Bs[tid >> 4][(tid & 15) * 4] = bv;
        __syncthreads();
#pragma unroll
        for (int kk = 0; kk < 16; kk++) {
            float4 a = *(const float4*)&As[kk][ty * 4];
            float4 b = *(const float4*)&Bs[kk][tx * 4];
            acc[0][0] += a.x * b.x; acc[0][1] += a.x * b.y; acc[0][2] += a.x * b.z; acc[0][3] += a.x * b.w;
            acc[1][0] += a.y * b.x; acc[1][1] += a.y * b.y; acc[1][2] += a.y * b.z; acc[1][3] += a.y * b.w;
            acc[2][0] += a.z * b.x; acc[2][1] += a.z * b.y; acc[2][2] += a.z * b.z; acc[2][3] += a.z * b.w;
            acc[3][0] += a.w * b.x; acc[3][1] += a.w * b.y; acc[3][2] += a.w * b.z; acc[3][3] += a.w * b.w;
        }
        __syncthreads();
    }

    float4 bv = make_float4(0.f, 0.f, 0.f, 0.f);
    if (bias) bv = *(const float4*)(bias + col0 + tx * 4);
#pragma unroll
    for (int i = 0; i < 4; i++) {
        int r = row0 + ty * 4 + i;
        if (r < M) {
            float4 o;
            o.x = acc[i][0] + bv.x;
            o.y = acc[i][1] + bv.y;
            o.z = acc[i][2] + bv.z;
            o.w = acc[i][3] + bv.w;
            if (doRelu) {
                o.x = fmaxf(o.x, 0.f); o.y = fmaxf(o.y, 0.f);
                o.z = fmaxf(o.z, 0.f); o.w = fmaxf(o.w, 0.f);
            }
            *(float4*)(C + (size_t)r * Nf + col0 + tx * 4) = o;
        }
    }
}

// ---------------------------------------------------------------------------
// Prep kernels
// ---------------------------------------------------------------------------
__global__ void cvt_bf16_2(const float* __restrict__ a, ushort_t* __restrict__ oa, int na,
                           const float* __restrict__ b, ushort_t* __restrict__ ob, int nb)
{
    int i = blockIdx.x * blockDim.x + threadIdx.x;
    if (i < na) oa[i] = f2bf(a[i]);
    else if (i - na < nb) ob[i - na] = f2bf(b[i - na]);
}

__global__ __launch_bounds__(256) void transpose_cast(
    const float* __restrict__ in, int K, int Nn,
    ushort_t* __restrict__ out, int ostride, int koff,
    int inBatchStride, int outBatchStride)
{
    __shared__ float tile[32][33];
    in  += (size_t)blockIdx.z * inBatchStride;
    out += (size_t)blockIdx.z * outBatchStride;
    int k0 = blockIdx.y * 32, n0 = blockIdx.x * 32;
    int tx = threadIdx.x & 31, ty = threadIdx.x >> 5;
#pragma unroll
    for (int j = 0; j < 4; j++)
        tile[ty + j * 8][tx] = in[(size_t)(k0 + ty + j * 8) * Nn + n0 + tx];
    __syncthreads();
#pragma unroll
    for (int j = 0; j < 4; j++) {
        int n = n0 + ty + j * 8;
        out[(size_t)n * ostride + koff + k0 + tx] = f2bf(tile[tx][ty + j * 8]);
    }
}

// Wqk[l][j][d] = (1/16) * sum_c Wq[l][d][c] * kbuf[l][j][c]
__global__ __launch_bounds__(256) void wqk_build(
    const float* __restrict__ Wq, const float* __restrict__ kbufs,
    float* __restrict__ wqk)
{
    int j = blockIdx.x, l = blockIdx.y;
    int d = threadIdx.x;
    __shared__ float kk[CDIM];
    kk[d] = kbufs[((size_t)l * MSLOT + j) * CDIM + d];
    __syncthreads();
    const float* wrow = Wq + ((size_t)l * CDIM + d) * CDIM;
    float acc = 0.f;
#pragma unroll 4
    for (int c = 0; c < CDIM; c++) acc += wrow[c] * kk[c];
    wqk[((size_t)l * MSLOT + j) * CDIM + d] = acc * 0.0625f;
}

// ---------------------------------------------------------------------------
// CSR construction
// ---------------------------------------------------------------------------
__global__ void count_deg(const int* __restrict__ dst, int* __restrict__ deg, int ne)
{
    int e = blockIdx.x * blockDim.x + threadIdx.x;
    if (e < ne) atomicAdd(&deg[dst[e]], 1);
}

__global__ __launch_bounds__(1024) void scan_kernel(const int* __restrict__ deg,
                                                    int* __restrict__ offs, int n)
{
    __shared__ int swt[16];
    int tid = threadIdx.x, lane = tid & 63, wid = tid >> 6;
    int base = tid * 20;
    int v[20];
    int s = 0;
#pragma unroll
    for (int i = 0; i < 20; i++) {
        int d = (base + i < n) ? deg[base + i] : 0;
        v[i] = d; s += d;
    }
    int x = s;
#pragma unroll
    for (int d = 1; d < 64; d <<= 1) {
        int t = __shfl_up(x, d);
        if (lane >= d) x += t;
    }
    if (lane == 63) swt[wid] = x;
    __syncthreads();
    if (wid == 0) {
        int w = (lane < 16) ? swt[lane] : 0;
#pragma unroll
        for (int d = 1; d < 16; d <<= 1) {
            int t = __shfl_up(w, d);
            if (lane >= d) w += t;
        }
        if (lane < 16) swt[lane] = w;
    }
    __syncthreads();
    int wbase = (wid == 0) ? 0 : swt[wid - 1];
    int run = wbase + x - s;
#pragma unroll
    for (int i = 0; i < 20; i++) {
        if (base + i < n) offs[base + i] = run;
        run += v[i];
    }
}

__global__ void fill_csr(const int* __restrict__ src, const int* __restrict__ dst,
                         const int* __restrict__ offs, int* __restrict__ cursor,
                         int* __restrict__ csr_src, int ne)
{
    int e = blockIdx.x * blockDim.x + threadIdx.x;
    if (e < ne) {
        int d = dst[e];
        int p = atomicAdd(&cursor[d], 1);
        csr_src[offs[d] + p] = src[e];
    }
}

// ---------------------------------------------------------------------------
// Fully fused GAT + cross-attn. h in fp8 e4m3. ALL gather loads (esrc + h)
// issued upfront; __launch_bounds__(256,4) gives the allocator 128 VGPRs so
// the prefetches stay in registers instead of being sunk to use points.
// out = relu(gat + softmax(gat.Wqk).v + node_in)
// ---------------------------------------------------------------------------
__global__ __launch_bounds__(256, 4) void gat_agg_fused(
    const uchar_t* __restrict__ h, const float* __restrict__ esrc, const float* __restrict__ edst,
    const int* __restrict__ offs, const int* __restrict__ deg, const int* __restrict__ csr_src,
    const float* __restrict__ wqk, const float* __restrict__ vbuf,
    const ushort_t* __restrict__ node_in,
    ushort_t* __restrict__ node_out, int n)
{
    int tid = threadIdx.x;
    int lane = tid & 63;
    int wslot = tid >> 6;
    int node = blockIdx.x * 4 + wslot;
    int start = offs[node], cnt = deg[node];
    int chead = lane >> 3;

    ushort4 c4 = *(const ushort4*)(node_in + (size_t)node * CDIM + lane * 4);

    float4 gat4;
    if (cnt <= 64) {
        int eh = lane >> 3, hh = lane & 7;
        float edl = edst[(size_t)node * NHEAD + hh];
        int sl = (lane < cnt) ? csr_src[start + lane] : 0;
        int nit = (cnt + 7) >> 3;
        int npf = nit < 4 ? nit : 4;

        // ---- issue ALL gather loads upfront (addresses depend only on sl) ----
        float es[8];
#pragma unroll
        for (int it = 0; it < 8; it++) {
            es[it] = 0.f;
            if (it < nit) {
                int e = it * 8 + eh;
                int se = __shfl(sl, e);
                es[it] = esrc[(size_t)se * NHEAD + hh];
            }
        }
        unsigned int hw[4][8];
#pragma unroll
        for (int rr = 0; rr < 4; rr++) {
            if (rr < npf) {
#pragma unroll
                for (int k = 0; k < 8; k++) {
                    int sv = __shfl(sl, rr * 8 + k);
                    hw[rr][k] = *(const unsigned int*)(h + (size_t)sv * CDIM + lane * 4);
                }
            }
        }

        // ---- softmax (register-only math on es) ----
        float lg[8], w8[8];
        float m = -3.0e38f;
#pragma unroll
        for (int it = 0; it < 8; it++) {
            float v = -3.0e38f;
            if (it < nit) {
                int e = it * 8 + eh;
                if (e < cnt) {
                    float t = es[it] + edl;
                    v = t > 0.f ? t : 0.2f * t;
                }
            }
            lg[it] = v;
            m = fmaxf(m, v);
        }
        m = fmaxf(m, __shfl_xor(m, 8));
        m = fmaxf(m, __shfl_xor(m, 16));
        m = fmaxf(m, __shfl_xor(m, 32));
        float den = 0.f;
#pragma unroll
        for (int it = 0; it < 8; it++) {
            float w = 0.f;
            if (it < nit) {
                int e = it * 8 + eh;
                if (e < cnt) w = __expf(lg[it] - m);
            }
            w8[it] = w;
            den += w;
        }
        den += __shfl_xor(den, 8);
        den += __shfl_xor(den, 16);
        den += __shfl_xor(den, 32);
        float inv = 1.f / (den + 1e-16f);
        float invc = __shfl(inv, chead);

        // ---- consume prefetched rows ----
        float4 acc = make_float4(0.f, 0.f, 0.f, 0.f);
#pragma unroll
        for (int rr = 0; rr < 4; rr++) {
            if (rr < npf) {
                float av[8];
#pragma unroll
                for (int k = 0; k < 8; k++)
                    av[k] = __shfl(w8[rr], (k << 3) | chead);
#pragma unroll
                for (int k = 0; k < 8; k++) {
                    floatx2 lo = __builtin_amdgcn_cvt_pk_f32_fp8((int)hw[rr][k], false);
                    floatx2 hi = __builtin_amdgcn_cvt_pk_f32_fp8((int)hw[rr][k], true);
                    acc.x += av[k] * lo.x;
                    acc.y += av[k] * lo.y;
                    acc.z += av[k] * hi.x;
                    acc.w += av[k] * hi.y;
                }
            }
        }
        // tail rounds (deg > 32, rare)
        for (int rr = 4; rr < nit; rr++) {
            int sv[8]; float av[8];
#pragma unroll
            for (int k = 0; k < 8; k++) {
                sv[k] = __shfl(sl, rr * 8 + k);
                av[k] = __shfl(w8[rr], (k << 3) | chead);
            }
#pragma unroll
            for (int k = 0; k < 8; k++) {
                unsigned int hwv = *(const unsigned int*)(h + (size_t)sv[k] * CDIM + lane * 4);
                floatx2 lo = __builtin_amdgcn_cvt_pk_f32_fp8((int)hwv, false);
                floatx2 hi = __builtin_amdgcn_cvt_pk_f32_fp8((int)hwv, true);
                acc.x += av[k] * lo.x;
                acc.y += av[k] * lo.y;
                acc.z += av[k] * hi.x;
                acc.w += av[k] * hi.y;
            }
        }
        gat4.x = fmaxf(acc.x * invc, 0.f);
        gat4.y = fmaxf(acc.y * invc, 0.f);
        gat4.z = fmaxf(acc.z * invc, 0.f);
        gat4.w = fmaxf(acc.w * invc, 0.f);
    } else {
        // slow path (deg > 64): two-pass serial (rare)
        int hh = lane & 7;
        float edl = edst[(size_t)node * NHEAD + hh];
        float m = -3.0e38f;
        int i8 = lane >> 3;
        for (int i = 0; i < cnt; i += 8) {
            int ii = i + i8;
            if (ii < cnt) {
                int s = csr_src[start + ii];
                float lgv = esrc[(size_t)s * NHEAD + hh] + edl;
                lgv = lgv > 0.f ? lgv : 0.2f * lgv;
                m = fmaxf(m, lgv);
            }
        }
        m = fmaxf(m, __shfl_xor(m, 8));
        m = fmaxf(m, __shfl_xor(m, 16));
        m = fmaxf(m, __shfl_xor(m, 32));
        float4 acc = make_float4(0.f, 0.f, 0.f, 0.f);
        float den = 0.f;
        for (int i = 0; i < cnt; i++) {
            int s = csr_src[start + i];
            float lgv = esrc[(size_t)s * NHEAD + hh] + edl;
            lgv = lgv > 0.f ? lgv : 0.2f * lgv;
            float w = __expf(lgv - m);
            den += w;
            float wc = __shfl(w, chead);
            unsigned int hwv = *(const unsigned int*)(h + (size_t)s * CDIM + lane * 4);
            floatx2 lo = __builtin_amdgcn_cvt_pk_f32_fp8((int)hwv, false);
            floatx2 hi = __builtin_amdgcn_cvt_pk_f32_fp8((int)hwv, true);
            acc.x += wc * lo.x; acc.y += wc * lo.y;
            acc.z += wc * hi.x; acc.w += wc * hi.y;
        }
        float dc = __shfl(den, chead) + 1e-16f;
        float inv = 1.f / dc;
        gat4.x = fmaxf(acc.x * inv, 0.f);
        gat4.y = fmaxf(acc.y * inv, 0.f);
        gat4.z = fmaxf(acc.z * inv, 0.f);
        gat4.w = fmaxf(acc.w * inv, 0.f);
    }

    // --- cross-attention epilogue: wqk/v direct from global (L2) ---
    float s[MSLOT];
#pragma unroll
    for (int j = 0; j < MSLOT; j++) {
        float4 w4 = *(const float4*)(wqk + j * CDIM + lane * 4);
        s[j] = gat4.x * w4.x + gat4.y * w4.y + gat4.z * w4.z + gat4.w * w4.w;
    }
#pragma unroll
    for (int d = 1; d < 64; d <<= 1) {
#pragma unroll
        for (int j = 0; j < MSLOT; j++) s[j] += __shfl_xor(s[j], d);
    }
    float m = s[0];
#pragma unroll
    for (int j = 1; j < MSLOT; j++) m = fmaxf(m, s[j]);
    float sum = 0.f;
#pragma unroll
    for (int j = 0; j < MSLOT; j++) { s[j] = __expf(s[j] - m); sum += s[j]; }
    float inv = 1.f / sum;

    float4 o;
    o.x = gat4.x + bf2f(c4.x); o.y = gat4.y + bf2f(c4.y);
    o.z = gat4.z + bf2f(c4.z); o.w = gat4.w + bf2f(c4.w);
#pragma unroll
    for (int j = 0; j < MSLOT; j++) {
        float p = s[j] * inv;
        float4 v4 = *(const float4*)(vbuf + j * CDIM + lane * 4);
        o.x += p * v4.x; o.y += p * v4.y; o.z += p * v4.z; o.w += p * v4.w;
    }
    o.x = fmaxf(o.x, 0.f); o.y = fmaxf(o.y, 0.f); o.z = fmaxf(o.z, 0.f); o.w = fmaxf(o.w, 0.f);
    ushort4 ob;
    ob.x = f2bf(o.x); ob.y = f2bf(o.y); ob.z = f2bf(o.z); ob.w = f2bf(o.w);
    *(ushort4*)(node_out + (size_t)node * CDIM + lane * 4) = ob;
}

// ---------------------------------------------------------------------------
// Pooling stage 1: per-block column partial sums. NO atomics.
__global__ __launch_bounds__(256) void col_part(const ushort_t* __restrict__ node,
                                                float* __restrict__ partial, int n)
{
    __shared__ __align__(16) float sred[4][CDIM];
    int tid = threadIdx.x;
    int lane = tid & 63, w = tid >> 6;
    int cg = lane * 4;
    int rows = (n + NBPOOL - 1) / NBPOOL;
    int r0 = blockIdx.x * rows;
    int r1 = r0 + rows; if (r1 > n) r1 = n;
    float4 acc = make_float4(0.f, 0.f, 0.f, 0.f);
    for (int r = r0 + w; r < r1; r += 4) {
        ushort4 v = *(const ushort4*)(node + (size_t)r * CDIM + cg);
        acc.x += bf2f(v.x); acc.y += bf2f(v.y); acc.z += bf2f(v.z); acc.w += bf2f(v.w);
    }
    *(float4*)&sred[w][cg] = acc;
    __syncthreads();
    float s = sred[0][tid] + sred[1][tid] + sred[2][tid] + sred[3][tid];
    partial[(size_t)blockIdx.x * CDIM + tid] = s;
}

// Pooling stage 2 + final projection. 256 threads.
__global__ __launch_bounds__(256) void finalize(
    const float* __restrict__ partial, const float* __restrict__ mem,
    const float* __restrict__ Wc, const float* __restrict__ bc,
    float* __restrict__ out)
{
    __shared__ float fv[CDIM + MDIM];
    __shared__ float r0s[4], r1s[4];
    int tid = threadIdx.x;
    if (tid < CDIM) {
        float s = 0.f;
        for (int b = 0; b < NBPOOL; b++) s += partial[(size_t)b * CDIM + tid];
        fv[tid] = s * (1.0f / (float)N_NODES);
    }
    if (tid < MDIM) {
        float s = 0.f;
        for (int r = 0; r < MSLOT; r++) s += mem[r * MDIM + tid];
        fv[CDIM + tid] = s * (1.0f / (float)MSLOT);
    }
    __syncthreads();
    float a0 = 0.f, a1 = 0.f;
    for (int i = tid; i < CDIM + MDIM; i += 256) {
        a0 += fv[i] * Wc[i * NCLS + 0];
        a1 += fv[i] * Wc[i * NCLS + 1];
    }
#pragma unroll
    for (int d = 1; d < 64; d <<= 1) { a0 += __shfl_xor(a0, d); a1 += __shfl_xor(a1, d); }
    if ((tid & 63) == 0) { r0s[tid >> 6] = a0; r1s[tid >> 6] = a1; }
    __syncthreads();
    if (tid == 0) {
        out[0] = r0s[0] + r0s[1] + r0s[2] + r0s[3] + bc[0];
        out[1] = r1s[0] + r1s[1] + r1s[2] + r1s[3] + bc[1];
    }
}

// ---------------------------------------------------------------------------
extern "C" void kernel_launch(void* const* d_in, const int* in_sizes, int n_in,
                              void* d_out, int out_size, void* d_ws, size_t ws_size,
                              hipStream_t stream)
{
    const float* x    = (const float*)d_in[0];
    const int*   ei   = (const int*)d_in[1];
    const float* temb = (const float*)d_in[2];
    const float* Wi   = (const float*)d_in[3];
    const float* bi   = (const float*)d_in[4];
    const float* Wg   = (const float*)d_in[5];
    const float* a_s  = (const float*)d_in[6];
    const float* a_d  = (const float*)d_in[7];
    const float* Wt   = (const float*)d_in[8];
    const float* Wq   = (const float*)d_in[9];
    const float* Wk   = (const float*)d_in[10];
    const float* Wv   = (const float*)d_in[11];
    const float* mem  = (const float*)d_in[12];
    const float* Wc   = (const float*)d_in[13];
    const float* bc   = (const float*)d_in[14];
    float* out = (float*)d_out;
    char* ws = (char*)d_ws;

    const size_t NCB_BYTES = (size_t)N_NODES * CDIM * 2;
    size_t off = 0;
    ushort_t* nodeA  = (ushort_t*)(ws + off); off += NCB_BYTES;
    ushort_t* nodeB  = (ushort_t*)(ws + off); off += NCB_BYTES;
    uchar_t*  hf8    = (uchar_t*)(ws + off);  off += (size_t)N_NODES * CDIM;
    ushort_t* xbf    = (ushort_t*)(ws + off); off += (size_t)N_NODES * FEAT * 2;
    ushort_t* tembbf = (ushort_t*)(ws + off); off += (size_t)N_NODES * TDIM * 2;
    float* esrc   = (float*)(ws + off); off += (size_t)N_NODES * NHEAD * 4;
    float* edst   = (float*)(ws + off); off += (size_t)N_NODES * NHEAD * 4;
    float* kbufs  = (float*)(ws + off); off += (size_t)NLAYER * MSLOT * CDIM * 4;
    float* vbufs  = (float*)(ws + off); off += (size_t)NLAYER * MSLOT * CDIM * 4;
    float* wqkL   = (float*)(ws + off); off += (size_t)NLAYER * MSLOT * CDIM * 4;
    float* Wtp    = (float*)(ws + off); off += (size_t)NLAYER * TDIM * CDIM * 4;
    ushort_t* Bt_i = (ushort_t*)(ws + off); off += (size_t)CDIM * FEAT * 2;
    ushort_t* Bt_h = (ushort_t*)(ws + off); off += (size_t)NLAYER * CDIM * (CDIM + TDIM) * 2;
    float* partial = (float*)(ws + off); off += (size_t)NBPOOL * CDIM * 4;
    size_t zero_base = off;
    int* deg      = (int*)(ws + off);   off += N_NODES * 4;
    int* cursor   = (int*)(ws + off);   off += N_NODES * 4;
    size_t zero_len = off - zero_base;
    int* offs     = (int*)(ws + off);   off += (N_NODES + 4) * 4;
    int* csr_src  = (int*)(ws + off);   off += (size_t)E_EDGES * 4;

    const int* srcIdx = ei;
    const int* dstIdx = ei + E_EDGES;

    hipMemsetAsync(ws + zero_base, 0, zero_len, stream);

    // ---- prep ----
    cvt_bf16_2<<<(N_NODES * (FEAT + TDIM) + 255) / 256, 256, 0, stream>>>(
        x, xbf, N_NODES * FEAT, temb, tembbf, N_NODES * TDIM);
    gemm64<<<dim3(4, 1, NLAYER), 256, 0, stream>>>(Wt, nullptr, Wg, nullptr, Wtp,
        TDIM, CDIM, CDIM, 0, TDIM * CDIM, CDIM * CDIM, TDIM * CDIM);
    transpose_cast<<<dim3(CDIM / 32, FEAT / 32, 1), 256, 0, stream>>>(
        Wi, FEAT, CDIM, Bt_i, FEAT, 0, 0, 0);
    transpose_cast<<<dim3(CDIM / 32, CDIM / 32, NLAYER), 256, 0, stream>>>(
        Wg, CDIM, CDIM, Bt_h, CDIM + TDIM, 0, CDIM * CDIM, CDIM * (CDIM + TDIM));
    transpose_cast<<<dim3(CDIM / 32, TDIM / 32, NLAYER), 256, 0, stream>>>(
        Wtp, TDIM, CDIM, Bt_h, CDIM + TDIM, CDIM, TDIM * CDIM, CDIM * (CDIM + TDIM));
    gemm64<<<dim3(4, 1, NLAYER), 256, 0, stream>>>(mem, nullptr, Wk, nullptr, kbufs,
        MSLOT, MDIM, CDIM, 0, 0, MDIM * CDIM, MSLOT * CDIM);
    gemm64<<<dim3(4, 1, NLAYER), 256, 0, stream>>>(mem, nullptr, Wv, nullptr, vbufs,
        MSLOT, MDIM, CDIM, 0, 0, MDIM * CDIM, MSLOT * CDIM);
    wqk_build<<<dim3(MSLOT, NLAYER), 256, 0, stream>>>(Wq, kbufs, wqkL);

    // ---- CSR ----
    count_deg<<<(E_EDGES + 255) / 256, 256, 0, stream>>>(dstIdx, deg, E_EDGES);
    scan_kernel<<<1, 1024, 0, stream>>>(deg, offs, N_NODES);
    fill_csr<<<(E_EDGES + 255) / 256, 256, 0, stream>>>(srcIdx, dstIdx, offs, cursor, csr_src, E_EDGES);

    dim3 mfmaGrid(2, N_NODES / 32);   // 2 x 625 = 1250 blocks
    int nodeBlocks = N_NODES / 4;

    // node = relu(x @ Wi + bi) -> nodeA (bf16)
    gemm_mfma<<<mfmaGrid, 256, 0, stream>>>(xbf, FEAT, FEAT, nullptr, 0, FEAT,
                                            Bt_i, bi, nodeA, 1);

    ushort_t* cur = nodeA;
    ushort_t* alt = nodeB;
    for (int l = 0; l < NLAYER; l++) {
        gemm_h<<<mfmaGrid, 256, 0, stream>>>(cur, CDIM, CDIM, tembbf, TDIM, CDIM + TDIM,
                                             Bt_h + (size_t)l * CDIM * (CDIM + TDIM),
                                             a_s + (size_t)l * CDIM, a_d + (size_t)l * CDIM,
                                             hf8, esrc, edst);
        gat_agg_fused<<<nodeBlocks, 256, 0, stream>>>(hf8, esrc, edst, offs, deg, csr_src,
                                                      wqkL + (size_t)l * MSLOT * CDIM,
                                                      vbufs + (size_t)l * MSLOT * CDIM,
                                                      cur, alt, N_NODES);
        ushort_t* t = cur; cur = alt; alt = t;
    }

    col_part<<<NBPOOL, 256, 0, stream>>>(cur, partial, N_NODES);
    finalize<<<1, 256, 0, stream>>>(partial, mem, Wc, bc, out);
}